// Round 5
// baseline (821.064 us; speedup 1.0000x reference)
//
#include <hip/hip_runtime.h>
#include <hip/hip_cooperative_groups.h>
namespace cg = cooperative_groups;

#define EPS_ 1e-8f

// sizes: B=16, N=2048, D=128, NS=8, H=128, steps=4
// ws layout (floats)
constexpr int OFF_WQT   = 0;
constexpr int OFF_WKT   = 16384;
constexpr int OFF_WIHT  = 32768;
constexpr int OFF_WHHT  = 81920;
constexpr int OFF_WM1T  = 131072;
constexpr int OFF_WM2T  = 147456;
constexpr int OFF_WO1T  = 163840;
constexpr int OFF_WO2T  = 229376;
constexpr int OFF_SLOTS = 262144;
constexpr int OFF_PI    = 294912;
constexpr int OFF_MUS   = 295040;
constexpr int OFF_WA    = 311424;
constexpr int OFF_WB    = 327808;
constexpr int OFF_CZ    = 344192;
constexpr int OFF_WUN   = 344320;   // 16*32*8*128 = 524288
constexpr int OFF_WS2   = 868608;
constexpr int OFF_WDEN  = 1392896;  // 4096
constexpr int OFF_K     = 1396992;  // fallback-only k buffer (4194304)

struct Args {
  const float *xin, *noise, *smu, *sls, *Wq, *Wk, *Wih, *Whh, *bih, *bhh,
              *Wm1, *bm1, *Wm2, *bm2, *gin, *bin, *gsl, *bsl, *gmu, *bmu,
              *Wo1, *bo1, *Wo2, *bo2;
  float* ws;
  float* out;
};

__device__ __forceinline__ void init_elem(int idx, const Args& a) {
  float* ws = a.ws;
  if (idx < 16384) { int j = idx >> 7, d = idx & 127; ws[OFF_WQT + d*128 + j] = a.Wq[idx]; return; }
  idx -= 16384;
  if (idx < 16384) { int j = idx >> 7, d = idx & 127; ws[OFF_WKT + d*128 + j] = a.Wk[idx]; return; }
  idx -= 16384;
  if (idx < 49152) { int j = idx >> 7, d = idx & 127; ws[OFF_WIHT + d*384 + j] = a.Wih[idx]; return; }
  idx -= 49152;
  if (idx < 49152) { int j = idx >> 7, d = idx & 127; ws[OFF_WHHT + d*384 + j] = a.Whh[idx]; return; }
  idx -= 49152;
  if (idx < 16384) { int j = idx >> 7, d = idx & 127; ws[OFF_WM1T + d*128 + j] = a.Wm1[idx]; return; }
  idx -= 16384;
  if (idx < 16384) { int j = idx >> 7, d = idx & 127; ws[OFF_WM2T + d*128 + j] = a.Wm2[idx]; return; }
  idx -= 16384;
  if (idx < 65536) { int j = idx >> 8, d = idx & 255; ws[OFF_WO1T + d*256 + j] = a.Wo1[idx]; return; }
  idx -= 65536;
  if (idx < 32768) { int j = idx >> 8, m = idx & 255; ws[OFF_WO2T + m*128 + j] = a.Wo2[idx]; return; }
  idx -= 32768;
  if (idx < 32768) { int c = idx & 255; ws[OFF_SLOTS + idx] = a.smu[c] + expf(a.sls[c]) * a.noise[idx]; return; }
  idx -= 32768;
  if (idx < 128) ws[OFF_PI + idx] = 0.125f;
}

struct ScrP1 {
  float xs[64][129];
  float2 red[64][8];
  float mrow[64], srow[64];
  float sl[256];
  float2 wr[4];
  float qs_l[128], ivs_l[128];
  float wrC[8];
};
struct ScrPA {
  float wAl[8][128], wBl[8][128];
  float gT[8][72];
  float pisl[8], czl[8];
  float pd[8][8];
  float recip[64];
  union { float pdots[8][64][8]; float pPf[4096]; } u;   // pP: [nh][a][sl][d] flat
  float es[64][8];
};
struct ScrPB {
  float redU[4][128], redS[4][128];
  float dred[32];
  float xs[128], hs[128];
  float gacc[4][6][128];
  float ga[6][128];
  float grus[128], hl[128], m1s[128];
  float macc[4][128];
  float2 wr2[2];
  float uarr[256];
  float2 wr4[4];
  float sln[256];
  float qacc[2][2][128];
  float qs_l[128], ivs_l[128];
  float wrC[8];
  float oacc[2][256];
  float hh[256];
};

__global__ __launch_bounds__(512, 4) void fused_kernel(Args a) {
  __shared__ float4 kc4[64 * 32];                       // 32KB persistent swizzled k tile
  __shared__ __align__(16) char scr_[41216];
  static_assert(sizeof(ScrP1) <= 41216, "p1");
  static_assert(sizeof(ScrPA) <= 41216, "pa");
  static_assert(sizeof(ScrPB) <= 41216, "pb");
  cg::grid_group grid = cg::this_grid();
  int t = threadIdx.x, bid = blockIdx.x;
  float* ws = a.ws;
  const int b = bid >> 5, chunk = bid & 31;

  // ================= P0: init (transposes + slots + pi) =================
  for (int idx = bid * 512 + t; idx < 295040; idx += 262144) init_elem(idx, a);
  grid.sync();

  // ================= P1: build own k tile (LN + GEMM) + initial s1 ======
  {
    ScrP1* p = (ScrP1*)scr_;
    const float* xrow = a.xin + (long long)(b * 2048 + chunk * 64) * 128;
    int r = t >> 3, cgi = t & 7;
    float vals[16], gl[16], bl[16];
    {
      const float4* s4 = (const float4*)(xrow + r * 128 + cgi * 16);
      *(float4*)&vals[0] = s4[0]; *(float4*)&vals[4]  = s4[1];
      *(float4*)&vals[8] = s4[2]; *(float4*)&vals[12] = s4[3];
      const float4* g4 = (const float4*)(a.gin + cgi * 16);
      const float4* b4 = (const float4*)(a.bin + cgi * 16);
      *(float4*)&gl[0] = g4[0]; *(float4*)&gl[4]  = g4[1];
      *(float4*)&gl[8] = g4[2]; *(float4*)&gl[12] = g4[3];
      *(float4*)&bl[0] = b4[0]; *(float4*)&bl[4]  = b4[1];
      *(float4*)&bl[8] = b4[2]; *(float4*)&bl[12] = b4[3];
    }
    {
      float s = 0.f, ss = 0.f;
      #pragma unroll
      for (int i = 0; i < 16; ++i) { float v = vals[i]; s += v; ss = fmaf(v, v, ss); }
      p->red[r][cgi] = make_float2(s, ss);
    }
    __syncthreads();
    if (t < 64) {
      float s = 0.f, ss = 0.f;
      #pragma unroll
      for (int c = 0; c < 8; ++c) { float2 pr = p->red[t][c]; s += pr.x; ss += pr.y; }
      float m = s * (1.0f / 128.0f);
      float var = ss * (1.0f / 128.0f) - m * m;
      p->mrow[t] = m; p->srow[t] = rsqrtf(var + 1e-5f);
    }
    __syncthreads();
    {
      float m = p->mrow[r], is = p->srow[r];
      #pragma unroll
      for (int i = 0; i < 16; ++i)
        p->xs[r][cgi * 16 + i] = (vals[i] - m) * is * gl[i] + bl[i];
    }
    __syncthreads();
    // GEMM: thread (rr = t&63 row, jg = t>>6 j-group of 16)
    {
      const float* WkT = ws + OFF_WKT;
      int rr = t & 63, jg = t >> 6;
      float acc[16];
      #pragma unroll
      for (int i = 0; i < 16; ++i) acc[i] = 0.f;
      #pragma unroll 2
      for (int d = 0; d < 128; ++d) {
        float xv = p->xs[rr][d];
        const float4* w4 = (const float4*)(WkT + d * 128 + jg * 16);
        #pragma unroll
        for (int i = 0; i < 4; ++i) {
          float4 wv = w4[i];
          acc[i * 4 + 0] = fmaf(xv, wv.x, acc[i * 4 + 0]);
          acc[i * 4 + 1] = fmaf(xv, wv.y, acc[i * 4 + 1]);
          acc[i * 4 + 2] = fmaf(xv, wv.z, acc[i * 4 + 2]);
          acc[i * 4 + 3] = fmaf(xv, wv.w, acc[i * 4 + 3]);
        }
      }
      #pragma unroll
      for (int gi = 0; gi < 4; ++gi)
        kc4[rr * 32 + ((jg * 4 + gi) ^ (rr & 31))] =
            make_float4(acc[gi * 4], acc[gi * 4 + 1], acc[gi * 4 + 2], acc[gi * 4 + 3]);
    }
    // ---- initial s1 (blocks 0..127 only; unit bi = bid)
    if (bid < 128) {
      __syncthreads();
      const float* WqT = ws + OFF_WQT;
      float v = 0.f;
      if (t < 256) {
        v = ws[OFF_SLOTS + bid * 256 + t];
        float s = v, ss = v * v;
        #pragma unroll
        for (int o = 32; o > 0; o >>= 1) { s += __shfl_down(s, o); ss += __shfl_down(ss, o); }
        if ((t & 63) == 0) p->wr[t >> 6] = make_float2(s, ss);
      }
      __syncthreads();
      if (t < 256) {
        float fs  = p->wr[0].x + p->wr[1].x + p->wr[2].x + p->wr[3].x;
        float fss = p->wr[0].y + p->wr[1].y + p->wr[2].y + p->wr[3].y;
        float m   = fs * (1.0f / 256.0f);
        float var = fss * (1.0f / 256.0f) - m * m;
        p->sl[t] = (v - m) * rsqrtf(var + 1e-5f) * a.gsl[t] + a.bsl[t];
      }
      __syncthreads();
      if (t < 128) {
        float acc = 0.f;
        #pragma unroll 4
        for (int d = 0; d < 128; ++d) acc = fmaf(p->sl[d], WqT[d * 128 + t], acc);
        p->qs_l[t] = acc;
        ws[OFF_MUS + bid * 128 + t] = p->sl[t];
      } else if (t < 256) {
        int jj = t - 128;
        float acc = 0.f;
        #pragma unroll 4
        for (int d = 0; d < 128; ++d) acc = fmaf(p->sl[128 + d], WqT[d * 128 + jj], acc);
        p->ivs_l[jj] = expf(-2.0f * acc);
      }
      __syncthreads();
      if (t < 256) {
        float cp = 0.f;
        if (t < 128) {
          float iv = p->ivs_l[t], qv = p->qs_l[t];
          ws[OFF_WA + bid * 128 + t] = iv;
          ws[OFF_WB + bid * 128 + t] = -2.0f * qv * iv;
          cp = qv * qv * iv;
        }
        #pragma unroll
        for (int o = 32; o > 0; o >>= 1) cp += __shfl_down(cp, o);
        if ((t & 63) == 0) p->wrC[t >> 6] = cp;
      }
      __syncthreads();
      if (t == 0) ws[OFF_CZ + bid] = p->wrC[0] + p->wrC[1];
    }
  }
  grid.sync();

  // ================= 4 iterations =================
  for (int step = 0; step < 4; ++step) {
    // ---- PA: dots -> gamma -> partials (all 512 blocks)
    {
      ScrPA* p = (ScrPA*)scr_;
      if (t < 256)      ((float4*)p->wAl)[t]       = ((const float4*)(ws + OFF_WA + b * 1024))[t];
      else              ((float4*)p->wBl)[t - 256] = ((const float4*)(ws + OFF_WB + b * 1024))[t - 256];
      if (t < 8) { p->pisl[t] = ws[OFF_PI + b * 8 + t]; p->czl[t] = ws[OFF_CZ + b * 8 + t]; }
      __syncthreads();
      // phase 1: thread (n = t&63, w = t>>6 -> 16 d's)
      {
        int n = t & 63, w = t >> 6;
        float acc[8] = {0, 0, 0, 0, 0, 0, 0, 0};
        const float4* wa4 = (const float4*)p->wAl;
        const float4* wb4 = (const float4*)p->wBl;
        #pragma unroll 2
        for (int dq = 0; dq < 4; ++dq) {
          int g = w * 4 + dq;
          float4 kv = kc4[n * 32 + (g ^ (n & 31))];
          float xx = kv.x * kv.x, yy = kv.y * kv.y, zz = kv.z * kv.z, ww2 = kv.w * kv.w;
          #pragma unroll
          for (int s8 = 0; s8 < 8; ++s8) {
            float4 a4 = wa4[s8 * 32 + g];
            float4 b4 = wb4[s8 * 32 + g];
            float ac = acc[s8];
            ac = fmaf(xx, a4.x, ac); ac = fmaf(kv.x, b4.x, ac);
            ac = fmaf(yy, a4.y, ac); ac = fmaf(kv.y, b4.y, ac);
            ac = fmaf(zz, a4.z, ac); ac = fmaf(kv.z, b4.z, ac);
            ac = fmaf(ww2, a4.w, ac); ac = fmaf(kv.w, b4.w, ac);
            acc[s8] = ac;
          }
        }
        *(float4*)&p->u.pdots[w][n][0] = make_float4(acc[0], acc[1], acc[2], acc[3]);
        *(float4*)&p->u.pdots[w][n][4] = make_float4(acc[4], acc[5], acc[6], acc[7]);
      }
      __syncthreads();
      int n2 = t >> 3, s8b = t & 7;
      float e;
      {
        float dots = p->czl[s8b];
        #pragma unroll
        for (int w = 0; w < 8; ++w) dots += p->u.pdots[w][n2][s8b];
        e = (expf(-dots) + EPS_) * p->pisl[s8b];
        p->es[n2][s8b] = e;
      }
      __syncthreads();
      if (t < 64) {
        float sm = 0.f;
        #pragma unroll
        for (int s8 = 0; s8 < 8; ++s8) sm += p->es[t][s8];
        p->recip[t] = 1.0f / sm;
      }
      __syncthreads();
      {
        float gam = e * p->recip[n2];
        p->gT[s8b][n2] = gam;
        float pp = gam;
        pp += __shfl_down(pp, 8); pp += __shfl_down(pp, 16); pp += __shfl_down(pp, 32);
        if ((t & 63) < 8) p->pd[t >> 6][t & 7] = pp;
      }
      __syncthreads();
      // phase 2: thread (d4 = t&31 granule, sl = (t>>5)&7, nh = t>>8)
      {
        int d4 = t & 31, sl = (t >> 5) & 7, nh = t >> 8;
        float4 ua = {0, 0, 0, 0}, qa = {0, 0, 0, 0};
        #pragma unroll 2
        for (int n = nh * 32; n < nh * 32 + 32; ++n) {
          float4 kv = kc4[n * 32 + (d4 ^ (n & 31))];
          float gam = p->gT[sl][n];
          ua.x = fmaf(gam, kv.x, ua.x); qa.x = fmaf(gam, kv.x * kv.x, qa.x);
          ua.y = fmaf(gam, kv.y, ua.y); qa.y = fmaf(gam, kv.y * kv.y, qa.y);
          ua.z = fmaf(gam, kv.z, ua.z); qa.z = fmaf(gam, kv.z * kv.z, qa.z);
          ua.w = fmaf(gam, kv.w, ua.w); qa.w = fmaf(gam, kv.w * kv.w, qa.w);
        }
        ((float4*)p->u.pPf)[(nh * 2 + 0) * 256 + sl * 32 + d4] = ua;
        ((float4*)p->u.pPf)[(nh * 2 + 1) * 256 + sl * 32 + d4] = qa;
      }
      __syncthreads();
      {
        long long pbase = (long long)(b * 32 + chunk) * 1024;
        const float4* pp4 = (const float4*)p->u.pPf;
        if (t < 256) {
          float4 x0 = pp4[t], x1 = pp4[512 + t];
          ((float4*)(ws + OFF_WUN + pbase))[t] =
              make_float4(x0.x + x1.x, x0.y + x1.y, x0.z + x1.z, x0.w + x1.w);
        } else {
          int tt = t - 256;
          float4 x0 = pp4[256 + tt], x1 = pp4[768 + tt];
          ((float4*)(ws + OFF_WS2 + pbase))[tt] =
              make_float4(x0.x + x1.x, x0.y + x1.y, x0.z + x1.z, x0.w + x1.w);
        }
        if (t < 8) {
          float sd = 0.f;
          #pragma unroll
          for (int w = 0; w < 8; ++w) sd += p->pd[w][t];
          ws[OFF_WDEN + (b * 32 + chunk) * 8 + t] = sd;
        }
      }
    }
    grid.sync();
    // ---- PB: slot update (blocks 0..127)
    if (bid < 128) {
      ScrPB* p = (ScrPB*)scr_;
      const float* wun = ws + OFF_WUN;  const float* ws2 = ws + OFF_WS2;
      const float* wden = ws + OFF_WDEN;
      const float* WihT = ws + OFF_WIHT; const float* WhhT = ws + OFF_WHHT;
      const float* Wm1T = ws + OFF_WM1T; const float* Wm2T = ws + OFF_WM2T;
      const float* WqT  = ws + OFF_WQT;
      const float* Wo1T = ws + OFF_WO1T; const float* Wo2T = ws + OFF_WO2T;
      int bi = bid, d = t & 127, qn = t >> 7;
      int b3 = bi >> 3, i3 = bi & 7;
      float unp = 0.f, s2p = 0.f;
      #pragma unroll
      for (int c = qn * 8; c < qn * 8 + 8; ++c) {
        int po = ((b3 * 32 + c) * 8 + i3) * 128 + d;
        unp += wun[po]; s2p += ws2[po];
      }
      p->redU[qn][d] = unp; p->redS[qn][d] = s2p;
      if (t < 32) p->dred[t] = wden[(b3 * 32 + t) * 8 + i3];
      if (qn == 1) p->hs[d] = ws[OFF_MUS + bi * 128 + d];
      __syncthreads();
      float den = 0.f;
      #pragma unroll
      for (int c = 0; c < 32; ++c) den += p->dred[c];
      float un  = p->redU[0][d] + p->redU[1][d] + p->redU[2][d] + p->redU[3][d];
      float s2v = p->redS[0][d] + p->redS[1][d] + p->redS[2][d] + p->redS[3][d];
      if (qn == 0) p->xs[d] = un / den;
      __syncthreads();
      {
        float a0 = 0, a1 = 0, a2 = 0, a3 = 0, a4 = 0, a5 = 0;
        #pragma unroll 4
        for (int dd = qn * 32; dd < qn * 32 + 32; ++dd) {
          float xv = p->xs[dd], hv = p->hs[dd];
          const float* wi = &WihT[dd * 384 + d];
          const float* wh = &WhhT[dd * 384 + d];
          a0 = fmaf(xv, wi[0], a0);  a1 = fmaf(xv, wi[128], a1); a2 = fmaf(xv, wi[256], a2);
          a3 = fmaf(hv, wh[0], a3);  a4 = fmaf(hv, wh[128], a4); a5 = fmaf(hv, wh[256], a5);
        }
        p->gacc[qn][0][d] = a0; p->gacc[qn][1][d] = a1; p->gacc[qn][2][d] = a2;
        p->gacc[qn][3][d] = a3; p->gacc[qn][4][d] = a4; p->gacc[qn][5][d] = a5;
      }
      __syncthreads();
      for (int f = t; f < 768; f += 512) {
        int j = f >> 7, dd = f & 127;
        p->ga[j][dd] = p->gacc[0][j][dd] + p->gacc[1][j][dd] + p->gacc[2][j][dd] + p->gacc[3][j][dd];
      }
      __syncthreads();
      float gru = 0.f;
      if (qn == 0) {
        float ir = p->ga[0][d] + a.bih[d], iz = p->ga[1][d] + a.bih[128 + d], inn = p->ga[2][d] + a.bih[256 + d];
        float hr = p->ga[3][d] + a.bhh[d], hz = p->ga[4][d] + a.bhh[128 + d], hn = p->ga[5][d] + a.bhh[256 + d];
        float r  = 1.0f / (1.0f + expf(-(ir + hr)));
        float z  = 1.0f / (1.0f + expf(-(iz + hz)));
        float nn = tanhf(inn + r * hn);
        gru = (1.0f - z) * nn + z * p->hs[d];
        p->grus[d] = gru;
        float s = gru, ssq = gru * gru;
        #pragma unroll
        for (int o = 32; o > 0; o >>= 1) { s += __shfl_down(s, o); ssq += __shfl_down(ssq, o); }
        if ((d & 63) == 0) p->wr2[d >> 6] = make_float2(s, ssq);
      }
      __syncthreads();
      if (qn == 0) {
        float fs = p->wr2[0].x + p->wr2[1].x, fss = p->wr2[0].y + p->wr2[1].y;
        float mean = fs * (1.0f / 128.0f);
        float var  = fss * (1.0f / 128.0f) - mean * mean;
        p->hl[d] = (gru - mean) * rsqrtf(var + 1e-5f) * a.gmu[d] + a.bmu[d];
      }
      __syncthreads();
      {
        float m1p = 0.f;
        #pragma unroll 4
        for (int dd = qn * 32; dd < qn * 32 + 32; ++dd)
          m1p = fmaf(p->hl[dd], Wm1T[dd * 128 + d], m1p);
        p->macc[qn][d] = m1p;
      }
      __syncthreads();
      if (qn == 0)
        p->m1s[d] = fmaxf(p->macc[0][d] + p->macc[1][d] + p->macc[2][d] + p->macc[3][d] + a.bm1[d], 0.f);
      __syncthreads();
      {
        float m2p = 0.f;
        #pragma unroll 4
        for (int dd = qn * 32; dd < qn * 32 + 32; ++dd)
          m2p = fmaf(p->m1s[dd], Wm2T[dd * 128 + d], m2p);
        p->macc[qn][d] = m2p;
      }
      __syncthreads();
      if (qn == 0) {
        float u = p->grus[d] + p->macc[0][d] + p->macc[1][d] + p->macc[2][d] + p->macc[3][d] + a.bm2[d];
        float val = (s2v - 2.0f * u * un + u * u * den) / den;
        float ls = 0.5f * logf(fmaxf(val, 0.0f) + EPS_);
        ws[OFF_SLOTS + bi * 256 + d]       = u;
        ws[OFF_SLOTS + bi * 256 + 128 + d] = ls;
        p->uarr[d] = u; p->uarr[128 + d] = ls;
        if (d == 0) ws[OFF_PI + bi] = den;
      }
      __syncthreads();
      if (step < 3) {
        float v2 = 0.f;
        if (t < 256) {
          v2 = p->uarr[t];
          float s = v2, ssq = v2 * v2;
          #pragma unroll
          for (int o = 32; o > 0; o >>= 1) { s += __shfl_down(s, o); ssq += __shfl_down(ssq, o); }
          if ((t & 63) == 0) p->wr4[t >> 6] = make_float2(s, ssq);
        }
        __syncthreads();
        if (t < 256) {
          float fs  = p->wr4[0].x + p->wr4[1].x + p->wr4[2].x + p->wr4[3].x;
          float fss = p->wr4[0].y + p->wr4[1].y + p->wr4[2].y + p->wr4[3].y;
          float m   = fs * (1.0f / 256.0f);
          float var = fss * (1.0f / 256.0f) - m * m;
          p->sln[t] = (v2 - m) * rsqrtf(var + 1e-5f) * a.gsl[t] + a.bsl[t];
        }
        __syncthreads();
        {
          int h2 = t >> 8, qq = (t >> 7) & 1, d2 = t & 127;
          const float* src = p->sln + h2 * 128;
          float acc = 0.f;
          #pragma unroll 4
          for (int dd = qq * 64; dd < qq * 64 + 64; ++dd)
            acc = fmaf(src[dd], WqT[dd * 128 + d2], acc);
          p->qacc[h2][qq][d2] = acc;
        }
        __syncthreads();
        if (t < 128) {
          p->qs_l[t] = p->qacc[0][0][t] + p->qacc[0][1][t];
          ws[OFF_MUS + bi * 128 + t] = p->sln[t];
        } else if (t < 256) {
          int dd2 = t - 128;
          p->ivs_l[dd2] = expf(-2.0f * (p->qacc[1][0][dd2] + p->qacc[1][1][dd2]));
        }
        __syncthreads();
        if (t < 256) {
          float cp = 0.f;
          if (t < 128) {
            float iv = p->ivs_l[t], qv = p->qs_l[t];
            ws[OFF_WA + bi * 128 + t] = iv;
            ws[OFF_WB + bi * 128 + t] = -2.0f * qv * iv;
            cp = qv * qv * iv;
          }
          #pragma unroll
          for (int o = 32; o > 0; o >>= 1) cp += __shfl_down(cp, o);
          if ((t & 63) == 0) p->wrC[t >> 6] = cp;
        }
        __syncthreads();
        if (t == 0) ws[OFF_CZ + bi] = p->wrC[0] + p->wrC[1];
      } else {
        // final output MLP
        {
          int o = t & 255, qq = t >> 8;
          float acc = 0.f;
          #pragma unroll 4
          for (int dd = qq * 128; dd < qq * 128 + 128; ++dd)
            acc = fmaf(p->uarr[dd], Wo1T[dd * 256 + o], acc);
          p->oacc[qq][o] = acc;
        }
        __syncthreads();
        if (t < 256) p->hh[t] = fmaxf(p->oacc[0][t] + p->oacc[1][t] + a.bo1[t], 0.f);
        __syncthreads();
        {
          int o2 = t & 127, q4 = t >> 7;
          float acc2 = 0.f;
          #pragma unroll 4
          for (int dd = q4 * 64; dd < q4 * 64 + 64; ++dd)
            acc2 = fmaf(p->hh[dd], Wo2T[dd * 128 + o2], acc2);
          p->macc[q4][o2] = acc2;
        }
        __syncthreads();
        if (t < 128)
          a.out[bi * 128 + t] = p->macc[0][t] + p->macc[1][t] + p->macc[2][t] + p->macc[3][t] + a.bo2[t];
      }
    }
    if (step < 3) grid.sync();
  }
}

// ===========================================================================
// Fallback path (round-4 kernels) in case cooperative launch is rejected
// ===========================================================================
__global__ __launch_bounds__(256) void init_kernel_fb(Args a) {
  int idx = blockIdx.x * 256 + threadIdx.x;
  if (idx < 295040) init_elem(idx, a);
}

__global__ __launch_bounds__(256) void k_kernel_fb(
    const float* __restrict__ xin, const float* __restrict__ g, const float* __restrict__ bb,
    const float* __restrict__ WkT, float* __restrict__ kout) {
  __shared__ float xsT[128][32];
  __shared__ float2 red[32][8];
  __shared__ float mrow[32], srow[32];
  int t = threadIdx.x;
  long long base = (long long)blockIdx.x * 32 * 128;
  int row = t >> 3, cg = t & 7;
  const float4* src = (const float4*)(xin + base + row * 128 + cg * 16);
  float4 v0 = src[0], v1 = src[1], v2 = src[2], v3 = src[3];
  const float4* g4p = (const float4*)(g + cg * 16);
  const float4* b4p = (const float4*)(bb + cg * 16);
  float vals[16], gl[16], bl[16];
  *(float4*)&vals[0] = v0; *(float4*)&vals[4] = v1; *(float4*)&vals[8] = v2; *(float4*)&vals[12] = v3;
  *(float4*)&gl[0] = g4p[0]; *(float4*)&gl[4] = g4p[1]; *(float4*)&gl[8] = g4p[2]; *(float4*)&gl[12] = g4p[3];
  *(float4*)&bl[0] = b4p[0]; *(float4*)&bl[4] = b4p[1]; *(float4*)&bl[8] = b4p[2]; *(float4*)&bl[12] = b4p[3];
  {
    float s = 0.f, ss = 0.f;
    #pragma unroll
    for (int i = 0; i < 16; ++i) { float v = vals[i]; s += v; ss = fmaf(v, v, ss); }
    red[row][cg] = make_float2(s, ss);
  }
  __syncthreads();
  if (t < 32) {
    float s = 0.f, ss = 0.f;
    #pragma unroll
    for (int c = 0; c < 8; ++c) { float2 pr = red[t][c]; s += pr.x; ss += pr.y; }
    float m = s * (1.0f / 128.0f);
    float var = ss * (1.0f / 128.0f) - m * m;
    mrow[t] = m; srow[t] = rsqrtf(var + 1e-5f);
  }
  __syncthreads();
  {
    float m = mrow[row], is = srow[row];
    #pragma unroll
    for (int i = 0; i < 16; ++i) {
      int d = cg * 16 + i;
      int rs = row ^ (((d >> 2) & 7) << 2);
      xsT[d][rs] = (vals[i] - m) * is * gl[i] + bl[i];
    }
  }
  __syncthreads();
  int j = t & 127, rh = t >> 7;
  int r0 = rh * 16;
  float acc[16];
  #pragma unroll
  for (int i = 0; i < 16; ++i) acc[i] = 0.f;
  #pragma unroll 4
  for (int d = 0; d < 128; ++d) {
    float wv = WkT[d * 128 + j];
    int X = ((d >> 2) & 7) << 2;
    #pragma unroll
    for (int gi = 0; gi < 4; ++gi) {
      int off = (r0 + gi * 4) ^ X;
      float4 xv = *(const float4*)&xsT[d][off];
      acc[gi * 4 + 0] = fmaf(xv.x, wv, acc[gi * 4 + 0]);
      acc[gi * 4 + 1] = fmaf(xv.y, wv, acc[gi * 4 + 1]);
      acc[gi * 4 + 2] = fmaf(xv.z, wv, acc[gi * 4 + 2]);
      acc[gi * 4 + 3] = fmaf(xv.w, wv, acc[gi * 4 + 3]);
    }
  }
  #pragma unroll
  for (int i = 0; i < 16; ++i) kout[base + (long long)(r0 + i) * 128 + j] = acc[i];
}

__global__ __launch_bounds__(256) void s1_kernel_fb(
    const float* __restrict__ slots, const float* __restrict__ g, const float* __restrict__ bb,
    const float* __restrict__ WqT, float* __restrict__ mus,
    float* __restrict__ wA, float* __restrict__ wB, float* __restrict__ cz) {
  __shared__ float sl[256];
  __shared__ float2 wr[4];
  __shared__ float qs_l[128], ivs_l[128];
  __shared__ float wrC[4];
  int t = threadIdx.x, bi = blockIdx.x;
  float v = slots[bi * 256 + t];
  float s = v, ss = v * v;
  #pragma unroll
  for (int o = 32; o > 0; o >>= 1) { s += __shfl_down(s, o); ss += __shfl_down(ss, o); }
  if ((t & 63) == 0) wr[t >> 6] = make_float2(s, ss);
  __syncthreads();
  float fs  = wr[0].x + wr[1].x + wr[2].x + wr[3].x;
  float fss = wr[0].y + wr[1].y + wr[2].y + wr[3].y;
  float m   = fs * (1.0f / 256.0f);
  float var = fss * (1.0f / 256.0f) - m * m;
  float sn  = (v - m) * rsqrtf(var + 1e-5f) * g[t] + bb[t];
  sl[t] = sn;
  __syncthreads();
  if (t < 128) {
    float acc = 0.f;
    #pragma unroll 4
    for (int d = 0; d < 128; ++d) acc = fmaf(sl[d], WqT[d * 128 + t], acc);
    qs_l[t] = acc;
    mus[bi * 128 + t] = sn;
  } else {
    int jj = t - 128;
    float acc = 0.f;
    #pragma unroll 4
    for (int d = 0; d < 128; ++d) acc = fmaf(sl[128 + d], WqT[d * 128 + jj], acc);
    ivs_l[jj] = expf(-2.0f * acc);
  }
  __syncthreads();
  float cp = 0.f;
  if (t < 128) {
    float iv = ivs_l[t], q = qs_l[t];
    wA[bi * 128 + t] = iv;
    wB[bi * 128 + t] = -2.0f * q * iv;
    cp = q * q * iv;
  }
  #pragma unroll
  for (int o = 32; o > 0; o >>= 1) cp += __shfl_down(cp, o);
  if ((t & 63) == 0) wrC[t >> 6] = cp;
  __syncthreads();
  if (t == 0) cz[bi] = wrC[0] + wrC[1];
}

__global__ __launch_bounds__(512) void s2_kernel_fb(
    const float* __restrict__ kmat, const float* __restrict__ wA,
    const float* __restrict__ wB,  const float* __restrict__ cz,
    const float* __restrict__ pi,
    float* __restrict__ wun, float* __restrict__ ws2, float* __restrict__ wden) {
  __shared__ float pdots[8][64][8];
  __shared__ float es[64][8];
  __shared__ float recip[64];
  __shared__ float gT[8][72];
  __shared__ float pd[8][8];
  __shared__ float pisl[8], czl[8];
  int t = threadIdx.x;
  int chunk = blockIdx.x, b = blockIdx.y;
  if (t < 8) { pisl[t] = pi[b * 8 + t]; czl[t] = cz[b * 8 + t]; }
  {
    int n = t & 63, w = t >> 6;
    const float4* kr4 = (const float4*)(kmat + (long long)((b * 2048 + chunk * 64 + n) * 128 + w * 16));
    const float4* wa4 = (const float4*)(wA + b * 1024);
    const float4* wb4 = (const float4*)(wB + b * 1024);
    float acc[8] = {0, 0, 0, 0, 0, 0, 0, 0};
    #pragma unroll 2
    for (int dq = 0; dq < 4; ++dq) {
      float4 kv = kr4[dq];
      float xx = kv.x * kv.x, yy = kv.y * kv.y, zz = kv.z * kv.z, ww = kv.w * kv.w;
      #pragma unroll
      for (int s = 0; s < 8; ++s) {
        float4 a4 = wa4[s * 32 + w * 4 + dq];
        float4 b4 = wb4[s * 32 + w * 4 + dq];
        float ac = acc[s];
        ac = fmaf(xx, a4.x, ac); ac = fmaf(kv.x, b4.x, ac);
        ac = fmaf(yy, a4.y, ac); ac = fmaf(kv.y, b4.y, ac);
        ac = fmaf(zz, a4.z, ac); ac = fmaf(kv.z, b4.z, ac);
        ac = fmaf(ww, a4.w, ac); ac = fmaf(kv.w, b4.w, ac);
        acc[s] = ac;
      }
    }
    *(float4*)&pdots[w][n][0] = make_float4(acc[0], acc[1], acc[2], acc[3]);
    *(float4*)&pdots[w][n][4] = make_float4(acc[4], acc[5], acc[6], acc[7]);
  }
  __syncthreads();
  float e;
  {
    int n2 = t >> 3, s = t & 7;
    float dots = czl[s];
    #pragma unroll
    for (int w = 0; w < 8; ++w) dots += pdots[w][n2][s];
    e = (expf(-dots) + EPS_) * pisl[s];
    es[n2][s] = e;
  }
  __syncthreads();
  if (t < 64) {
    float ssum = 0.f;
    #pragma unroll
    for (int s = 0; s < 8; ++s) ssum += es[t][s];
    recip[t] = 1.0f / ssum;
  }
  __syncthreads();
  {
    int n2 = t >> 3, s = t & 7;
    float gam = e * recip[n2];
    gT[s][n2] = gam;
    float pp = gam;
    pp += __shfl_down(pp, 8); pp += __shfl_down(pp, 16); pp += __shfl_down(pp, 32);
    if ((t & 63) < 8) pd[t >> 6][t & 7] = pp;
  }
  __syncthreads();
  if (t < 8) {
    float sden = 0.f;
    #pragma unroll
    for (int w = 0; w < 8; ++w) sden += pd[w][t];
    wden[(b * 32 + chunk) * 8 + t] = sden;
  }
  {
    int d = t & 127, sh = t >> 7;
    int s0 = sh * 2, s1 = s0 + 1;
    const float* kcol = kmat + (long long)(b * 2048 + chunk * 64) * 128 + d;
    float u0 = 0.f, u1 = 0.f, q0 = 0.f, q1 = 0.f;
    #pragma unroll 2
    for (int n3 = 0; n3 < 64; n3 += 4) {
      float4 ga = *(const float4*)&gT[s0][n3];
      float4 gb = *(const float4*)&gT[s1][n3];
      float k0 = kcol[(n3 + 0) * 128];
      float k1 = kcol[(n3 + 1) * 128];
      float k2 = kcol[(n3 + 2) * 128];
      float k3 = kcol[(n3 + 3) * 128];
      float k0s = k0 * k0, k1s = k1 * k1, k2s = k2 * k2, k3s = k3 * k3;
      u0 = fmaf(ga.x, k0, u0); q0 = fmaf(ga.x, k0s, q0);
      u1 = fmaf(gb.x, k0, u1); q1 = fmaf(gb.x, k0s, q1);
      u0 = fmaf(ga.y, k1, u0); q0 = fmaf(ga.y, k1s, q0);
      u1 = fmaf(gb.y, k1, u1); q1 = fmaf(gb.y, k1s, q1);
      u0 = fmaf(ga.z, k2, u0); q0 = fmaf(ga.z, k2s, q0);
      u1 = fmaf(gb.z, k2, u1); q1 = fmaf(gb.z, k2s, q1);
      u0 = fmaf(ga.w, k3, u0); q0 = fmaf(ga.w, k3s, q0);
      u1 = fmaf(gb.w, k3, u1); q1 = fmaf(gb.w, k3s, q1);
    }
    int pb = ((b * 32 + chunk) * 8) * 128 + d;
    wun[pb + s0 * 128] = u0; wun[pb + s1 * 128] = u1;
    ws2[pb + s0 * 128] = q0; ws2[pb + s1 * 128] = q1;
  }
}

__global__ __launch_bounds__(512) void s3_kernel_fb(Args a, int step) {
  float* ws = a.ws;
  const float* wun = ws + OFF_WUN;   const float* ws2 = ws + OFF_WS2;
  const float* wden = ws + OFF_WDEN;
  const float* WihT = ws + OFF_WIHT; const float* WhhT = ws + OFF_WHHT;
  const float* Wm1T = ws + OFF_WM1T; const float* Wm2T = ws + OFF_WM2T;
  const float* WqT  = ws + OFF_WQT;
  const float* Wo1T = ws + OFF_WO1T; const float* Wo2T = ws + OFF_WO2T;
  __shared__ ScrPB pb_;
  ScrPB* p = &pb_;
  int t = threadIdx.x, bi = blockIdx.x;
  int d = t & 127, qn = t >> 7;
  int b3 = bi >> 3, i3 = bi & 7;
  float unp = 0.f, s2p = 0.f;
  #pragma unroll
  for (int c = qn * 8; c < qn * 8 + 8; ++c) {
    int po = ((b3 * 32 + c) * 8 + i3) * 128 + d;
    unp += wun[po]; s2p += ws2[po];
  }
  p->redU[qn][d] = unp; p->redS[qn][d] = s2p;
  if (t < 32) p->dred[t] = wden[(b3 * 32 + t) * 8 + i3];
  if (qn == 1) p->hs[d] = ws[OFF_MUS + bi * 128 + d];
  __syncthreads();
  float den = 0.f;
  #pragma unroll
  for (int c = 0; c < 32; ++c) den += p->dred[c];
  float un  = p->redU[0][d] + p->redU[1][d] + p->redU[2][d] + p->redU[3][d];
  float s2v = p->redS[0][d] + p->redS[1][d] + p->redS[2][d] + p->redS[3][d];
  if (qn == 0) p->xs[d] = un / den;
  __syncthreads();
  {
    float a0 = 0, a1 = 0, a2 = 0, a3 = 0, a4 = 0, a5 = 0;
    #pragma unroll 4
    for (int dd = qn * 32; dd < qn * 32 + 32; ++dd) {
      float xv = p->xs[dd], hv = p->hs[dd];
      const float* wi = &WihT[dd * 384 + d];
      const float* wh = &WhhT[dd * 384 + d];
      a0 = fmaf(xv, wi[0], a0);  a1 = fmaf(xv, wi[128], a1); a2 = fmaf(xv, wi[256], a2);
      a3 = fmaf(hv, wh[0], a3);  a4 = fmaf(hv, wh[128], a4); a5 = fmaf(hv, wh[256], a5);
    }
    p->gacc[qn][0][d] = a0; p->gacc[qn][1][d] = a1; p->gacc[qn][2][d] = a2;
    p->gacc[qn][3][d] = a3; p->gacc[qn][4][d] = a4; p->gacc[qn][5][d] = a5;
  }
  __syncthreads();
  for (int f = t; f < 768; f += 512) {
    int j = f >> 7, dd = f & 127;
    p->ga[j][dd] = p->gacc[0][j][dd] + p->gacc[1][j][dd] + p->gacc[2][j][dd] + p->gacc[3][j][dd];
  }
  __syncthreads();
  float gru = 0.f;
  if (qn == 0) {
    float ir = p->ga[0][d] + a.bih[d], iz = p->ga[1][d] + a.bih[128 + d], inn = p->ga[2][d] + a.bih[256 + d];
    float hr = p->ga[3][d] + a.bhh[d], hz = p->ga[4][d] + a.bhh[128 + d], hn = p->ga[5][d] + a.bhh[256 + d];
    float r  = 1.0f / (1.0f + expf(-(ir + hr)));
    float z  = 1.0f / (1.0f + expf(-(iz + hz)));
    float nn = tanhf(inn + r * hn);
    gru = (1.0f - z) * nn + z * p->hs[d];
    p->grus[d] = gru;
    float s = gru, ssq = gru * gru;
    #pragma unroll
    for (int o = 32; o > 0; o >>= 1) { s += __shfl_down(s, o); ssq += __shfl_down(ssq, o); }
    if ((d & 63) == 0) p->wr2[d >> 6] = make_float2(s, ssq);
  }
  __syncthreads();
  if (qn == 0) {
    float fs = p->wr2[0].x + p->wr2[1].x, fss = p->wr2[0].y + p->wr2[1].y;
    float mean = fs * (1.0f / 128.0f);
    float var  = fss * (1.0f / 128.0f) - mean * mean;
    p->hl[d] = (gru - mean) * rsqrtf(var + 1e-5f) * a.gmu[d] + a.bmu[d];
  }
  __syncthreads();
  {
    float m1p = 0.f;
    #pragma unroll 4
    for (int dd = qn * 32; dd < qn * 32 + 32; ++dd)
      m1p = fmaf(p->hl[dd], Wm1T[dd * 128 + d], m1p);
    p->macc[qn][d] = m1p;
  }
  __syncthreads();
  if (qn == 0)
    p->m1s[d] = fmaxf(p->macc[0][d] + p->macc[1][d] + p->macc[2][d] + p->macc[3][d] + a.bm1[d], 0.f);
  __syncthreads();
  {
    float m2p = 0.f;
    #pragma unroll 4
    for (int dd = qn * 32; dd < qn * 32 + 32; ++dd)
      m2p = fmaf(p->m1s[dd], Wm2T[dd * 128 + d], m2p);
    p->macc[qn][d] = m2p;
  }
  __syncthreads();
  if (qn == 0) {
    float u = p->grus[d] + p->macc[0][d] + p->macc[1][d] + p->macc[2][d] + p->macc[3][d] + a.bm2[d];
    float val = (s2v - 2.0f * u * un + u * u * den) / den;
    float ls = 0.5f * logf(fmaxf(val, 0.0f) + EPS_);
    ws[OFF_SLOTS + bi * 256 + d]       = u;
    ws[OFF_SLOTS + bi * 256 + 128 + d] = ls;
    p->uarr[d] = u; p->uarr[128 + d] = ls;
    if (d == 0) ws[OFF_PI + bi] = den;
  }
  __syncthreads();
  if (step < 3) {
    float v2 = 0.f;
    if (t < 256) {
      v2 = p->uarr[t];
      float s = v2, ssq = v2 * v2;
      #pragma unroll
      for (int o = 32; o > 0; o >>= 1) { s += __shfl_down(s, o); ssq += __shfl_down(ssq, o); }
      if ((t & 63) == 0) p->wr4[t >> 6] = make_float2(s, ssq);
    }
    __syncthreads();
    if (t < 256) {
      float fs  = p->wr4[0].x + p->wr4[1].x + p->wr4[2].x + p->wr4[3].x;
      float fss = p->wr4[0].y + p->wr4[1].y + p->wr4[2].y + p->wr4[3].y;
      float m   = fs * (1.0f / 256.0f);
      float var = fss * (1.0f / 256.0f) - m * m;
      p->sln[t] = (v2 - m) * rsqrtf(var + 1e-5f) * a.gsl[t] + a.bsl[t];
    }
    __syncthreads();
    {
      int h2 = t >> 8, qq = (t >> 7) & 1, d2 = t & 127;
      const float* src = p->sln + h2 * 128;
      float acc = 0.f;
      #pragma unroll 4
      for (int dd = qq * 64; dd < qq * 64 + 64; ++dd)
        acc = fmaf(src[dd], WqT[dd * 128 + d2], acc);
      p->qacc[h2][qq][d2] = acc;
    }
    __syncthreads();
    if (t < 128) {
      p->qs_l[t] = p->qacc[0][0][t] + p->qacc[0][1][t];
      ws[OFF_MUS + bi * 128 + t] = p->sln[t];
    } else if (t < 256) {
      int dd2 = t - 128;
      p->ivs_l[dd2] = expf(-2.0f * (p->qacc[1][0][dd2] + p->qacc[1][1][dd2]));
    }
    __syncthreads();
    if (t < 256) {
      float cp = 0.f;
      if (t < 128) {
        float iv = p->ivs_l[t], qv = p->qs_l[t];
        ws[OFF_WA + bi * 128 + t] = iv;
        ws[OFF_WB + bi * 128 + t] = -2.0f * qv * iv;
        cp = qv * qv * iv;
      }
      #pragma unroll
      for (int o = 32; o > 0; o >>= 1) cp += __shfl_down(cp, o);
      if ((t & 63) == 0) p->wrC[t >> 6] = cp;
    }
    __syncthreads();
    if (t == 0) ws[OFF_CZ + bi] = p->wrC[0] + p->wrC[1];
  } else {
    {
      int o = t & 255, qq = t >> 8;
      float acc = 0.f;
      #pragma unroll 4
      for (int dd = qq * 128; dd < qq * 128 + 128; ++dd)
        acc = fmaf(p->uarr[dd], Wo1T[dd * 256 + o], acc);
      p->oacc[qq][o] = acc;
    }
    __syncthreads();
    if (t < 256) p->hh[t] = fmaxf(p->oacc[0][t] + p->oacc[1][t] + a.bo1[t], 0.f);
    __syncthreads();
    {
      int o2 = t & 127, q4 = t >> 7;
      float acc2 = 0.f;
      #pragma unroll 4
      for (int dd = q4 * 64; dd < q4 * 64 + 64; ++dd)
        acc2 = fmaf(p->hh[dd], Wo2T[dd * 128 + o2], acc2);
      p->macc[q4][o2] = acc2;
    }
    __syncthreads();
    if (t < 128)
      a.out[bi * 128 + t] = p->macc[0][t] + p->macc[1][t] + p->macc[2][t] + p->macc[3][t] + a.bo2[t];
  }
}

// ---------------------------------------------------------------------------
extern "C" void kernel_launch(void* const* d_in, const int* in_sizes, int n_in,
                              void* d_out, int out_size, void* d_ws, size_t ws_size,
                              hipStream_t stream) {
  Args a;
  a.xin  = (const float*)d_in[0];  a.noise = (const float*)d_in[1];
  a.smu  = (const float*)d_in[2];  a.sls   = (const float*)d_in[3];
  a.Wq   = (const float*)d_in[4];  a.Wk    = (const float*)d_in[5];
  a.Wih  = (const float*)d_in[6];  a.Whh   = (const float*)d_in[7];
  a.bih  = (const float*)d_in[8];  a.bhh   = (const float*)d_in[9];
  a.Wm1  = (const float*)d_in[10]; a.bm1   = (const float*)d_in[11];
  a.Wm2  = (const float*)d_in[12]; a.bm2   = (const float*)d_in[13];
  a.gin  = (const float*)d_in[14]; a.bin   = (const float*)d_in[15];
  a.gsl  = (const float*)d_in[16]; a.bsl   = (const float*)d_in[17];
  a.gmu  = (const float*)d_in[18]; a.bmu   = (const float*)d_in[19];
  a.Wo1  = (const float*)d_in[20]; a.bo1   = (const float*)d_in[21];
  a.Wo2  = (const float*)d_in[22]; a.bo2   = (const float*)d_in[23];
  a.ws   = (float*)d_ws;
  a.out  = (float*)d_out;

  void* kargs[] = { (void*)&a };
  hipError_t err = hipLaunchCooperativeKernel((void*)fused_kernel, dim3(512), dim3(512),
                                              kargs, 0, stream);
  if (err != hipSuccess) {
    (void)hipGetLastError();  // clear error state; use fallback multi-kernel path
    float* ws = (float*)d_ws;
    hipLaunchKernelGGL(init_kernel_fb, dim3(1153), dim3(256), 0, stream, a);
    hipLaunchKernelGGL(k_kernel_fb, dim3(1024), dim3(256), 0, stream,
                       a.xin, a.gin, a.bin, ws + OFF_WKT, ws + OFF_K);
    hipLaunchKernelGGL(s1_kernel_fb, dim3(128), dim3(256), 0, stream,
                       ws + OFF_SLOTS, a.gsl, a.bsl, ws + OFF_WQT,
                       ws + OFF_MUS, ws + OFF_WA, ws + OFF_WB, ws + OFF_CZ);
    for (int s = 0; s < 4; ++s) {
      hipLaunchKernelGGL(s2_kernel_fb, dim3(32, 16), dim3(512), 0, stream,
                         ws + OFF_K, ws + OFF_WA, ws + OFF_WB, ws + OFF_CZ,
                         ws + OFF_PI, ws + OFF_WUN, ws + OFF_WS2, ws + OFF_WDEN);
      hipLaunchKernelGGL(s3_kernel_fb, dim3(128), dim3(512), 0, stream, a, s);
    }
  }
}

// Round 7
// 185.754 us; speedup vs baseline: 4.4202x; 4.4202x over previous
//
#include <hip/hip_runtime.h>

#define EPS_ 1e-8f

// sizes: B=16, N=2048, D=128, NS=8, H=128, steps=4
constexpr int OFF_K     = 0;                       // 16*2048*128 = 4194304
constexpr int OFF_WQT   = 4194304;                 // 16384
constexpr int OFF_WKT   = OFF_WQT  + 16384;
constexpr int OFF_WIHT  = OFF_WKT  + 16384;        // 49152
constexpr int OFF_WHHT  = OFF_WIHT + 49152;        // 49152
constexpr int OFF_WM1T  = OFF_WHHT + 49152;        // 16384
constexpr int OFF_WM2T  = OFF_WM1T + 16384;        // 16384
constexpr int OFF_WO1T  = OFF_WM2T + 16384;        // 65536
constexpr int OFF_WO2T  = OFF_WO1T + 65536;        // 32768
constexpr int OFF_SLOTS = OFF_WO2T + 32768;        // 32768
constexpr int OFF_PI    = OFF_SLOTS+ 32768;        // 128
constexpr int OFF_MUS   = OFF_PI   + 128;          // 16384
constexpr int OFF_WA    = OFF_MUS  + 16384;        // 16384 (iv)
constexpr int OFF_WB    = OFF_WA   + 16384;        // 16384 (-2*q*iv)
constexpr int OFF_UN    = OFF_WB   + 16384;        // 16*32*8*128 = 524288
constexpr int OFF_S2    = OFF_UN   + 524288;       // 524288
constexpr int OFF_DEN   = OFF_S2   + 524288;       // 16*32*8 = 4096
constexpr int OFF_CZ    = OFF_DEN  + 4096;         // 128

// ---------------------------------------------------------------------------
__global__ __launch_bounds__(256) void init_kernel(
    const float* __restrict__ Wq,  const float* __restrict__ Wk,
    const float* __restrict__ Wih, const float* __restrict__ Whh,
    const float* __restrict__ Wm1, const float* __restrict__ Wm2,
    const float* __restrict__ Wo1, const float* __restrict__ Wo2,
    const float* __restrict__ smu, const float* __restrict__ sls,
    const float* __restrict__ noise, float* __restrict__ ws) {
  int idx = blockIdx.x * 256 + threadIdx.x;
  if (idx < 16384) { int j = idx >> 7, d = idx & 127; ws[OFF_WQT + d*128 + j] = Wq[idx]; return; }
  idx -= 16384;
  if (idx < 16384) { int j = idx >> 7, d = idx & 127; ws[OFF_WKT + d*128 + j] = Wk[idx]; return; }
  idx -= 16384;
  if (idx < 49152) { int j = idx >> 7, d = idx & 127; ws[OFF_WIHT + d*384 + j] = Wih[idx]; return; }
  idx -= 49152;
  if (idx < 49152) { int j = idx >> 7, d = idx & 127; ws[OFF_WHHT + d*384 + j] = Whh[idx]; return; }
  idx -= 49152;
  if (idx < 16384) { int j = idx >> 7, d = idx & 127; ws[OFF_WM1T + d*128 + j] = Wm1[idx]; return; }
  idx -= 16384;
  if (idx < 16384) { int j = idx >> 7, d = idx & 127; ws[OFF_WM2T + d*128 + j] = Wm2[idx]; return; }
  idx -= 16384;
  if (idx < 65536) { int j = idx >> 8, d = idx & 255; ws[OFF_WO1T + d*256 + j] = Wo1[idx]; return; }
  idx -= 65536;
  if (idx < 32768) { int j = idx >> 8, m = idx & 255; ws[OFF_WO2T + m*128 + j] = Wo2[idx]; return; }
  idx -= 32768;
  if (idx < 32768) { int c = idx & 255; ws[OFF_SLOTS + idx] = smu[c] + expf(sls[c]) * noise[idx]; return; }
  idx -= 32768;
  if (idx < 128) { ws[OFF_PI + idx] = 0.125f; }
}

// ---------------------------------------------------------------------------
// k = LN(inputs) @ Wk.T : 64 rows/block, 512 blocks, 256 thr.
// x in LDS [64][129] -> b32 lane=row reads are conflict-free (2/bank = free).
// W read from global with WAVE-UNIFORM address (readfirstlane j-base) ->
// scalarizes to s_load / L1 broadcast; stays off the LDS pipe.
__global__ __launch_bounds__(256) void k_kernel(
    const float* __restrict__ xin, const float* __restrict__ g, const float* __restrict__ bb,
    const float* __restrict__ WkT, float* __restrict__ kout) {
  __shared__ float xs[64][129];
  __shared__ float2 red2[64][4];
  __shared__ float mrow[64], srow[64];
  int t = threadIdx.x;
  long long base = (long long)blockIdx.x * 64 * 128;
  const float4* in4 = (const float4*)(xin + base);
  for (int f = t; f < 2048; f += 256) {
    float4 v = in4[f];
    int r = f >> 5, c = (f & 31) * 4;
    xs[r][c] = v.x; xs[r][c + 1] = v.y; xs[r][c + 2] = v.z; xs[r][c + 3] = v.w;
  }
  __syncthreads();
  {
    int r = t >> 2, q = t & 3;
    float s = 0.f, ss = 0.f;
    #pragma unroll 8
    for (int u = 0; u < 32; ++u) { float v = xs[r][q * 32 + u]; s += v; ss = fmaf(v, v, ss); }
    red2[r][q] = make_float2(s, ss);
  }
  __syncthreads();
  if (t < 64) {
    float s = 0.f, ss = 0.f;
    #pragma unroll
    for (int q2 = 0; q2 < 4; ++q2) { float2 p = red2[t][q2]; s += p.x; ss += p.y; }
    float m = s * (1.0f / 128.0f);
    float var = ss * (1.0f / 128.0f) - m * m;
    mrow[t] = m; srow[t] = rsqrtf(var + 1e-5f);
  }
  __syncthreads();
  {
    int r = t >> 2, q = t & 3;
    float m = mrow[r], is = srow[r];
    #pragma unroll 8
    for (int u = 0; u < 32; ++u) {
      int d = q * 32 + u;
      xs[r][d] = (xs[r][d] - m) * is * g[d] + bb[d];
    }
  }
  __syncthreads();
  // GEMM: lane = row (b32 conflict-free), 32 j per thread, W wave-uniform
  int r = t & 63;
  int jb = __builtin_amdgcn_readfirstlane((t >> 6) * 32);
  float acc[32];
  #pragma unroll
  for (int i = 0; i < 32; ++i) acc[i] = 0.f;
  for (int d = 0; d < 128; ++d) {
    float xv = xs[r][d];
    const float* wrow = WkT + d * 128 + jb;   // uniform address
    #pragma unroll
    for (int i = 0; i < 8; ++i) {
      float4 wv = *(const float4*)(wrow + i * 4);
      acc[i * 4 + 0] = fmaf(xv, wv.x, acc[i * 4 + 0]);
      acc[i * 4 + 1] = fmaf(xv, wv.y, acc[i * 4 + 1]);
      acc[i * 4 + 2] = fmaf(xv, wv.z, acc[i * 4 + 2]);
      acc[i * 4 + 3] = fmaf(xv, wv.w, acc[i * 4 + 3]);
    }
  }
  __syncthreads();
  // stage accs back into xs (2-way free) then coalesced f4 store
  #pragma unroll 8
  for (int i = 0; i < 32; ++i) xs[r][jb + i] = acc[i];
  __syncthreads();
  float4* out4 = (float4*)(kout + base);
  for (int f = t; f < 2048; f += 256) {
    int rr = f >> 5, c = (f & 31) * 4;
    out4[f] = make_float4(xs[rr][c], xs[rr][c + 1], xs[rr][c + 2], xs[rr][c + 3]);
  }
}

// ---------------------------------------------------------------------------
// S1 standalone (first iteration): LN(slots) -> mus, wA=iv, wB=-2*q*iv, cz=sum q^2*iv
__global__ __launch_bounds__(256) void s1_kernel(
    const float* __restrict__ slots, const float* __restrict__ g, const float* __restrict__ bb,
    const float* __restrict__ WqT, float* __restrict__ mus,
    float* __restrict__ wA, float* __restrict__ wB, float* __restrict__ cz) {
  __shared__ float sl[256];
  __shared__ float2 wr[4];
  __shared__ float qs_l[128], ivs_l[128];
  __shared__ float wrC[4];
  int t = threadIdx.x, bi = blockIdx.x;
  float v = slots[bi * 256 + t];
  float s = v, ss = v * v;
  #pragma unroll
  for (int o = 32; o > 0; o >>= 1) { s += __shfl_down(s, o); ss += __shfl_down(ss, o); }
  if ((t & 63) == 0) wr[t >> 6] = make_float2(s, ss);
  __syncthreads();
  float fs  = wr[0].x + wr[1].x + wr[2].x + wr[3].x;
  float fss = wr[0].y + wr[1].y + wr[2].y + wr[3].y;
  float m   = fs * (1.0f/256.0f);
  float var = fss * (1.0f/256.0f) - m * m;
  float isr = rsqrtf(var + 1e-5f);
  float sn  = (v - m) * isr * g[t] + bb[t];
  sl[t] = sn;
  __syncthreads();
  if (t < 128) {
    float acc = 0.f;
    #pragma unroll 4
    for (int d = 0; d < 128; ++d) acc = fmaf(sl[d], WqT[d * 128 + t], acc);
    qs_l[t] = acc;
    mus[bi * 128 + t] = sn;
  } else {
    int jj = t - 128;
    float acc = 0.f;
    #pragma unroll 4
    for (int d = 0; d < 128; ++d) acc = fmaf(sl[128 + d], WqT[d * 128 + jj], acc);
    ivs_l[jj] = expf(-2.0f * acc);
  }
  __syncthreads();
  float cp = 0.f;
  if (t < 128) {
    float iv = ivs_l[t], q = qs_l[t];
    wA[bi * 128 + t] = iv;
    wB[bi * 128 + t] = -2.0f * q * iv;
    cp = q * q * iv;
  }
  #pragma unroll
  for (int o = 32; o > 0; o >>= 1) cp += __shfl_down(cp, o);
  if ((t & 63) == 0) wrC[t >> 6] = cp;
  __syncthreads();
  if (t == 0) cz[bi] = wrC[0] + wrC[1];
}

// ---------------------------------------------------------------------------
// S2 v3: 64-n chunk per block, 512 thr, no k in LDS.
// phase1 COALESCED: thread (w = t&7 fast, n = t>>3); d-granules g = i*8+w so
// each f4-load instruction covers contiguous 128B segments of 8 rows.
// wa/wb read from global (L1-resident 8KB), not LDS.
__global__ __launch_bounds__(512) void s2_kernel(
    const float* __restrict__ kmat, const float* __restrict__ wA,
    const float* __restrict__ wB,  const float* __restrict__ cz,
    const float* __restrict__ pi,
    float* __restrict__ wun, float* __restrict__ ws2, float* __restrict__ wden) {
  __shared__ float pdots[8][64][8];   // 16KB
  __shared__ float es[64][9];
  __shared__ float recip[64];
  __shared__ float gT[8][72];
  __shared__ float pd[8][8];
  __shared__ float pisl[8], czl[8];
  int t = threadIdx.x;
  int chunk = blockIdx.x, b = blockIdx.y;
  if (t < 8) { pisl[t] = pi[b * 8 + t]; czl[t] = cz[b * 8 + t]; }
  // ---- phase 1: thread (w = t&7, n = t>>3)
  {
    int w = t & 7, n = t >> 3;
    const float4* kr4 = (const float4*)(kmat + (long long)(b * 2048 + chunk * 64 + n) * 128);
    const float4* wa4 = (const float4*)(wA + b * 1024);
    const float4* wb4 = (const float4*)(wB + b * 1024);
    float acc[8] = {0, 0, 0, 0, 0, 0, 0, 0};
    #pragma unroll
    for (int i = 0; i < 4; ++i) {
      int gg = i * 8 + w;
      float4 kv = kr4[gg];
      float xx = kv.x * kv.x, yy = kv.y * kv.y, zz = kv.z * kv.z, ww2 = kv.w * kv.w;
      #pragma unroll
      for (int s = 0; s < 8; ++s) {
        float4 a4 = wa4[s * 32 + gg];
        float4 b4 = wb4[s * 32 + gg];
        float ac = acc[s];
        ac = fmaf(xx, a4.x, ac); ac = fmaf(kv.x, b4.x, ac);
        ac = fmaf(yy, a4.y, ac); ac = fmaf(kv.y, b4.y, ac);
        ac = fmaf(zz, a4.z, ac); ac = fmaf(kv.z, b4.z, ac);
        ac = fmaf(ww2, a4.w, ac); ac = fmaf(kv.w, b4.w, ac);
        acc[s] = ac;
      }
    }
    *(float4*)&pdots[w][n][0] = make_float4(acc[0], acc[1], acc[2], acc[3]);
    *(float4*)&pdots[w][n][4] = make_float4(acc[4], acc[5], acc[6], acc[7]);
  }
  __syncthreads();
  // ---- reduce over d-chunks + exp ; thread (n2 = t>>3, s = t&7)
  float e;
  {
    int n2 = t >> 3, s = t & 7;
    float dots = czl[s];
    #pragma unroll
    for (int w = 0; w < 8; ++w) dots += pdots[w][n2][s];
    e = (expf(-dots) + EPS_) * pisl[s];
    es[n2][s] = e;
  }
  __syncthreads();
  if (t < 64) {
    float ssum = 0.f;
    #pragma unroll
    for (int s = 0; s < 8; ++s) ssum += es[t][s];
    recip[t] = 1.0f / ssum;
  }
  __syncthreads();
  // ---- gammas + den partials
  {
    int n2 = t >> 3, s = t & 7;
    float gam = e * recip[n2];
    gT[s][n2] = gam;
    float p = gam;
    p += __shfl_down(p, 8); p += __shfl_down(p, 16); p += __shfl_down(p, 32);
    if ((t & 63) < 8) pd[t >> 6][t & 7] = p;
  }
  __syncthreads();
  if (t < 8) {
    float sden = 0.f;
    #pragma unroll
    for (int w = 0; w < 8; ++w) sden += pd[w][t];
    wden[(b * 32 + chunk) * 8 + t] = sden;
  }
  // ---- phase 2: thread (d = t&127, sh = t>>7 -> slots 2sh, 2sh+1)
  {
    int d = t & 127, sh = t >> 7;
    int s0 = sh * 2, s1 = s0 + 1;
    const float* kcol = kmat + (long long)(b * 2048 + chunk * 64) * 128 + d;
    float u0 = 0.f, u1 = 0.f, q0 = 0.f, q1 = 0.f;
    #pragma unroll 2
    for (int n3 = 0; n3 < 64; n3 += 4) {
      float4 ga = *(const float4*)&gT[s0][n3];
      float4 gb = *(const float4*)&gT[s1][n3];
      float k0 = kcol[(n3 + 0) * 128];
      float k1 = kcol[(n3 + 1) * 128];
      float k2 = kcol[(n3 + 2) * 128];
      float k3 = kcol[(n3 + 3) * 128];
      float k0s = k0 * k0, k1s = k1 * k1, k2s = k2 * k2, k3s = k3 * k3;
      u0 = fmaf(ga.x, k0, u0); q0 = fmaf(ga.x, k0s, q0);
      u1 = fmaf(gb.x, k0, u1); q1 = fmaf(gb.x, k0s, q1);
      u0 = fmaf(ga.y, k1, u0); q0 = fmaf(ga.y, k1s, q0);
      u1 = fmaf(gb.y, k1, u1); q1 = fmaf(gb.y, k1s, q1);
      u0 = fmaf(ga.z, k2, u0); q0 = fmaf(ga.z, k2s, q0);
      u1 = fmaf(gb.z, k2, u1); q1 = fmaf(gb.z, k2s, q1);
      u0 = fmaf(ga.w, k3, u0); q0 = fmaf(ga.w, k3s, q0);
      u1 = fmaf(gb.w, k3, u1); q1 = fmaf(gb.w, k3s, q1);
    }
    int pb = ((b * 32 + chunk) * 8) * 128 + d;
    wun[pb + s0 * 128] = u0; wun[pb + s1 * 128] = u1;
    ws2[pb + s0 * 128] = q0; ws2[pb + s1 * 128] = q1;
  }
}

// ---------------------------------------------------------------------------
// S3 fused: reduce(32 chunks) + GRU + LN + MLP + upd_ls + slots/pi; then
// next-iter S1 (emitting wA/wB/cz) or the final output MLP.
__global__ __launch_bounds__(512) void s3_kernel(
    const float* __restrict__ wun, const float* __restrict__ ws2, const float* __restrict__ wden,
    const float* __restrict__ WihT, const float* __restrict__ WhhT,
    const float* __restrict__ bih,  const float* __restrict__ bhh,
    const float* __restrict__ Wm1T, const float* __restrict__ bm1,
    const float* __restrict__ Wm2T, const float* __restrict__ bm2,
    const float* __restrict__ gmu,  const float* __restrict__ bmu,
    float* __restrict__ slots, float* __restrict__ pi,
    int do_s1,
    const float* __restrict__ gs, const float* __restrict__ bs,
    const float* __restrict__ WqT,
    float* __restrict__ mus, float* __restrict__ wAo, float* __restrict__ wBo,
    float* __restrict__ czo,
    const float* __restrict__ Wo1T, const float* __restrict__ bo1,
    const float* __restrict__ Wo2T, const float* __restrict__ bo2,
    float* __restrict__ out) {
  int t = threadIdx.x, bi = blockIdx.x;
  int d = t & 127, q = t >> 7;      // q in [0,4)
  int b = bi >> 3, i = bi & 7;
  __shared__ float redU[4][128], redS[4][128];
  __shared__ float dred[32];
  __shared__ float xs[128], hs[128];
  __shared__ float gacc[4][6][128];
  __shared__ float ga[6][128];
  __shared__ float grus[128], hl[128], m1s[128];
  __shared__ float macc[4][128];
  __shared__ float2 wr2[2];
  __shared__ float uarr[256];
  float unp = 0.f, s2p = 0.f;
  #pragma unroll
  for (int c = q * 8; c < q * 8 + 8; ++c) {
    int po = ((b * 32 + c) * 8 + i) * 128 + d;
    unp += wun[po]; s2p += ws2[po];
  }
  redU[q][d] = unp; redS[q][d] = s2p;
  if (t < 32) dred[t] = wden[(b * 32 + t) * 8 + i];
  if (q == 1) hs[d] = mus[bi * 128 + d];
  __syncthreads();
  float den = 0.f;
  #pragma unroll
  for (int c = 0; c < 32; ++c) den += dred[c];
  float un  = redU[0][d] + redU[1][d] + redU[2][d] + redU[3][d];
  float s2v = redS[0][d] + redS[1][d] + redS[2][d] + redS[3][d];
  if (q == 0) xs[d] = un / den;
  __syncthreads();
  {
    float a0 = 0, a1 = 0, a2 = 0, a3 = 0, a4 = 0, a5 = 0;
    #pragma unroll 4
    for (int dd = q * 32; dd < q * 32 + 32; ++dd) {
      float xv = xs[dd], hv = hs[dd];
      const float* wi = &WihT[dd * 384 + d];
      const float* wh = &WhhT[dd * 384 + d];
      a0 = fmaf(xv, wi[0],   a0);
      a1 = fmaf(xv, wi[128], a1);
      a2 = fmaf(xv, wi[256], a2);
      a3 = fmaf(hv, wh[0],   a3);
      a4 = fmaf(hv, wh[128], a4);
      a5 = fmaf(hv, wh[256], a5);
    }
    gacc[q][0][d] = a0; gacc[q][1][d] = a1; gacc[q][2][d] = a2;
    gacc[q][3][d] = a3; gacc[q][4][d] = a4; gacc[q][5][d] = a5;
  }
  __syncthreads();
  for (int f = t; f < 768; f += 512) {
    int j = f >> 7, dd = f & 127;
    ga[j][dd] = gacc[0][j][dd] + gacc[1][j][dd] + gacc[2][j][dd] + gacc[3][j][dd];
  }
  __syncthreads();
  float gru = 0.f;
  if (q == 0) {
    float ir = ga[0][d] + bih[d], iz = ga[1][d] + bih[128 + d], inn = ga[2][d] + bih[256 + d];
    float hr = ga[3][d] + bhh[d], hz = ga[4][d] + bhh[128 + d], hn  = ga[5][d] + bhh[256 + d];
    float r  = 1.0f / (1.0f + expf(-(ir + hr)));
    float z  = 1.0f / (1.0f + expf(-(iz + hz)));
    float nn = tanhf(inn + r * hn);
    gru = (1.0f - z) * nn + z * hs[d];
    grus[d] = gru;
    float s = gru, ssq = gru * gru;
    #pragma unroll
    for (int o = 32; o > 0; o >>= 1) { s += __shfl_down(s, o); ssq += __shfl_down(ssq, o); }
    if ((d & 63) == 0) wr2[d >> 6] = make_float2(s, ssq);
  }
  __syncthreads();
  if (q == 0) {
    float fs = wr2[0].x + wr2[1].x, fss = wr2[0].y + wr2[1].y;
    float mean = fs * (1.0f/128.0f);
    float var  = fss * (1.0f/128.0f) - mean * mean;
    hl[d] = (gru - mean) * rsqrtf(var + 1e-5f) * gmu[d] + bmu[d];
  }
  __syncthreads();
  {
    float m1p = 0.f;
    #pragma unroll 4
    for (int dd = q * 32; dd < q * 32 + 32; ++dd)
      m1p = fmaf(hl[dd], Wm1T[dd * 128 + d], m1p);
    macc[q][d] = m1p;
  }
  __syncthreads();
  if (q == 0) m1s[d] = fmaxf(macc[0][d] + macc[1][d] + macc[2][d] + macc[3][d] + bm1[d], 0.f);
  __syncthreads();
  {
    float m2p = 0.f;
    #pragma unroll 4
    for (int dd = q * 32; dd < q * 32 + 32; ++dd)
      m2p = fmaf(m1s[dd], Wm2T[dd * 128 + d], m2p);
    macc[q][d] = m2p;
  }
  __syncthreads();
  if (q == 0) {
    float u = grus[d] + macc[0][d] + macc[1][d] + macc[2][d] + macc[3][d] + bm2[d];
    float val = (s2v - 2.0f * u * un + u * u * den) / den;
    float ls = 0.5f * logf(fmaxf(val, 0.0f) + EPS_);
    slots[bi * 256 + d]       = u;
    slots[bi * 256 + 128 + d] = ls;
    uarr[d] = u; uarr[128 + d] = ls;
    if (d == 0) pi[bi] = den;
  }
  __syncthreads();
  if (do_s1) {
    __shared__ float2 wr4[4];
    __shared__ float sln[256];
    __shared__ float qacc[2][2][128];
    __shared__ float qs_l[128], ivs_l[128];
    __shared__ float wrC[8];
    if (t < 256) {
      float v2 = uarr[t];
      float s = v2, ssq = v2 * v2;
      #pragma unroll
      for (int o = 32; o > 0; o >>= 1) { s += __shfl_down(s, o); ssq += __shfl_down(ssq, o); }
      if ((t & 63) == 0) wr4[t >> 6] = make_float2(s, ssq);
    }
    __syncthreads();
    if (t < 256) {
      float fs  = wr4[0].x + wr4[1].x + wr4[2].x + wr4[3].x;
      float fss = wr4[0].y + wr4[1].y + wr4[2].y + wr4[3].y;
      float m   = fs * (1.0f/256.0f);
      float var = fss * (1.0f/256.0f) - m * m;
      sln[t] = (uarr[t] - m) * rsqrtf(var + 1e-5f) * gs[t] + bs[t];
    }
    __syncthreads();
    {
      int h2 = t >> 8, qq = (t >> 7) & 1, d2 = t & 127;
      const float* src = sln + h2 * 128;
      float acc = 0.f;
      #pragma unroll 4
      for (int dd = qq * 64; dd < qq * 64 + 64; ++dd)
        acc = fmaf(src[dd], WqT[dd * 128 + d2], acc);
      qacc[h2][qq][d2] = acc;
    }
    __syncthreads();
    if (t < 128) {
      qs_l[t] = qacc[0][0][t] + qacc[0][1][t];
      mus[bi * 128 + t] = sln[t];
    } else if (t < 256) {
      int dd2 = t - 128;
      ivs_l[dd2] = expf(-2.0f * (qacc[1][0][dd2] + qacc[1][1][dd2]));
    }
    __syncthreads();
    float cp = 0.f;
    if (t < 128) {
      float iv = ivs_l[t], qv = qs_l[t];
      wAo[bi * 128 + t] = iv;
      wBo[bi * 128 + t] = -2.0f * qv * iv;
      cp = qv * qv * iv;
    }
    #pragma unroll
    for (int o = 32; o > 0; o >>= 1) cp += __shfl_down(cp, o);
    if ((t & 63) == 0) wrC[t >> 6] = cp;
    __syncthreads();
    if (t == 0) czo[bi] = wrC[0] + wrC[1];
  } else {
    __shared__ float oacc[2][256];
    __shared__ float hh[256];
    {
      int o = t & 255, qq = t >> 8;
      float acc = 0.f;
      #pragma unroll 4
      for (int dd = qq * 128; dd < qq * 128 + 128; ++dd)
        acc = fmaf(uarr[dd], Wo1T[dd * 256 + o], acc);
      oacc[qq][o] = acc;
    }
    __syncthreads();
    if (t < 256) hh[t] = fmaxf(oacc[0][t] + oacc[1][t] + bo1[t], 0.f);
    __syncthreads();
    {
      int o2 = t & 127, q4 = t >> 7;
      float acc2 = 0.f;
      #pragma unroll 4
      for (int dd = q4 * 64; dd < q4 * 64 + 64; ++dd)
        acc2 = fmaf(hh[dd], Wo2T[dd * 128 + o2], acc2);
      macc[q4][o2] = acc2;
    }
    __syncthreads();
    if (t < 128) out[bi * 128 + t] = macc[0][t] + macc[1][t] + macc[2][t] + macc[3][t] + bo2[t];
  }
}

// ---------------------------------------------------------------------------
extern "C" void kernel_launch(void* const* d_in, const int* in_sizes, int n_in,
                              void* d_out, int out_size, void* d_ws, size_t ws_size,
                              hipStream_t stream) {
  const float* inputs = (const float*)d_in[0];
  const float* noise  = (const float*)d_in[1];
  const float* smu    = (const float*)d_in[2];
  const float* sls    = (const float*)d_in[3];
  const float* Wq     = (const float*)d_in[4];
  const float* Wk     = (const float*)d_in[5];
  const float* Wih    = (const float*)d_in[6];
  const float* Whh    = (const float*)d_in[7];
  const float* bih    = (const float*)d_in[8];
  const float* bhh    = (const float*)d_in[9];
  const float* Wm1    = (const float*)d_in[10];
  const float* bm1    = (const float*)d_in[11];
  const float* Wm2    = (const float*)d_in[12];
  const float* bm2    = (const float*)d_in[13];
  const float* gin    = (const float*)d_in[14];
  const float* bin    = (const float*)d_in[15];
  const float* gsl    = (const float*)d_in[16];
  const float* bsl    = (const float*)d_in[17];
  const float* gmu    = (const float*)d_in[18];
  const float* bmu    = (const float*)d_in[19];
  const float* Wo1    = (const float*)d_in[20];
  const float* bo1    = (const float*)d_in[21];
  const float* Wo2    = (const float*)d_in[22];
  const float* bo2    = (const float*)d_in[23];

  float* ws    = (float*)d_ws;
  float* kbuf  = ws + OFF_K;
  float* WqT   = ws + OFF_WQT;
  float* WkT   = ws + OFF_WKT;
  float* WihT  = ws + OFF_WIHT;
  float* WhhT  = ws + OFF_WHHT;
  float* Wm1T  = ws + OFF_WM1T;
  float* Wm2T  = ws + OFF_WM2T;
  float* Wo1T  = ws + OFF_WO1T;
  float* Wo2T  = ws + OFF_WO2T;
  float* slots = ws + OFF_SLOTS;
  float* pibuf = ws + OFF_PI;
  float* mus   = ws + OFF_MUS;
  float* wA    = ws + OFF_WA;
  float* wB    = ws + OFF_WB;
  float* wun   = ws + OFF_UN;
  float* ws2   = ws + OFF_S2;
  float* wden  = ws + OFF_DEN;
  float* czb   = ws + OFF_CZ;

  hipLaunchKernelGGL(init_kernel, dim3(1153), dim3(256), 0, stream,
                     Wq, Wk, Wih, Whh, Wm1, Wm2, Wo1, Wo2, smu, sls, noise, ws);
  hipLaunchKernelGGL(k_kernel, dim3(512), dim3(256), 0, stream,
                     inputs, gin, bin, WkT, kbuf);
  hipLaunchKernelGGL(s1_kernel, dim3(128), dim3(256), 0, stream,
                     slots, gsl, bsl, WqT, mus, wA, wB, czb);
  for (int s = 0; s < 4; ++s) {
    hipLaunchKernelGGL(s2_kernel, dim3(32, 16), dim3(512), 0, stream,
                       kbuf, wA, wB, czb, pibuf, wun, ws2, wden);
    hipLaunchKernelGGL(s3_kernel, dim3(128), dim3(512), 0, stream,
                       wun, ws2, wden, WihT, WhhT, bih, bhh,
                       Wm1T, bm1, Wm2T, bm2, gmu, bmu, slots, pibuf,
                       (s < 3) ? 1 : 0, gsl, bsl, WqT, mus, wA, wB, czb,
                       Wo1T, bo1, Wo2T, bo2, (float*)d_out);
  }
}

// Round 8
// 178.207 us; speedup vs baseline: 4.6074x; 1.0423x over previous
//
#include <hip/hip_runtime.h>

#define EPS_ 1e-8f

// sizes: B=16, N=2048, D=128, NS=8, H=128, steps=4
constexpr int OFF_K     = 0;                       // 16*2048*128 = 4194304
constexpr int OFF_WQT   = 4194304;                 // 16384
constexpr int OFF_WKT   = OFF_WQT  + 16384;
constexpr int OFF_WIHT  = OFF_WKT  + 16384;        // 49152
constexpr int OFF_WHHT  = OFF_WIHT + 49152;        // 49152
constexpr int OFF_WM1T  = OFF_WHHT + 49152;        // 16384
constexpr int OFF_WM2T  = OFF_WM1T + 16384;        // 16384
constexpr int OFF_WO1T  = OFF_WM2T + 16384;        // 65536
constexpr int OFF_WO2T  = OFF_WO1T + 65536;        // 32768
constexpr int OFF_SLOTS = OFF_WO2T + 32768;        // 32768
constexpr int OFF_PI    = OFF_SLOTS+ 32768;        // 128
constexpr int OFF_MUS   = OFF_PI   + 128;          // 16384
constexpr int OFF_WA    = OFF_MUS  + 16384;        // 16384 (iv)
constexpr int OFF_WB    = OFF_WA   + 16384;        // 16384 (-2*q*iv)
constexpr int OFF_UN    = OFF_WB   + 16384;        // 16*32*8*128 = 524288
constexpr int OFF_S2    = OFF_UN   + 524288;       // 524288
constexpr int OFF_DEN   = OFF_S2   + 524288;       // 16*32*8 = 4096
constexpr int OFF_CZ    = OFF_DEN  + 4096;         // 128

// ---------------------------------------------------------------------------
__global__ __launch_bounds__(256) void init_kernel(
    const float* __restrict__ Wq,  const float* __restrict__ Wk,
    const float* __restrict__ Wih, const float* __restrict__ Whh,
    const float* __restrict__ Wm1, const float* __restrict__ Wm2,
    const float* __restrict__ Wo1, const float* __restrict__ Wo2,
    const float* __restrict__ smu, const float* __restrict__ sls,
    const float* __restrict__ noise, float* __restrict__ ws) {
  int idx = blockIdx.x * 256 + threadIdx.x;
  if (idx < 16384) { int j = idx >> 7, d = idx & 127; ws[OFF_WQT + d*128 + j] = Wq[idx]; return; }
  idx -= 16384;
  if (idx < 16384) { int j = idx >> 7, d = idx & 127; ws[OFF_WKT + d*128 + j] = Wk[idx]; return; }
  idx -= 16384;
  if (idx < 49152) { int j = idx >> 7, d = idx & 127; ws[OFF_WIHT + d*384 + j] = Wih[idx]; return; }
  idx -= 49152;
  if (idx < 49152) { int j = idx >> 7, d = idx & 127; ws[OFF_WHHT + d*384 + j] = Whh[idx]; return; }
  idx -= 49152;
  if (idx < 16384) { int j = idx >> 7, d = idx & 127; ws[OFF_WM1T + d*128 + j] = Wm1[idx]; return; }
  idx -= 16384;
  if (idx < 16384) { int j = idx >> 7, d = idx & 127; ws[OFF_WM2T + d*128 + j] = Wm2[idx]; return; }
  idx -= 16384;
  if (idx < 65536) { int j = idx >> 8, d = idx & 255; ws[OFF_WO1T + d*256 + j] = Wo1[idx]; return; }
  idx -= 65536;
  if (idx < 32768) { int j = idx >> 8, m = idx & 255; ws[OFF_WO2T + m*128 + j] = Wo2[idx]; return; }
  idx -= 32768;
  if (idx < 32768) { int c = idx & 255; ws[OFF_SLOTS + idx] = smu[c] + expf(sls[c]) * noise[idx]; return; }
  idx -= 32768;
  if (idx < 128) { ws[OFF_PI + idx] = 0.125f; }
}

// ---------------------------------------------------------------------------
// k = LN(inputs) @ Wk.T : 16 rows/block, 2048 blocks (8/CU -> 32 waves/CU).
// GEMM: thread = (j4 = t&31 -> 4 j via ONE coalesced b128 W load per d,
//                 rg = t>>5 -> 2 rows via 2 broadcast LDS b32 reads).
// 256 LDS instr/thread, 128 independent b128 W loads -> deep pipelining.
__global__ __launch_bounds__(256) void k_kernel(
    const float* __restrict__ xin, const float* __restrict__ g, const float* __restrict__ bb,
    const float* __restrict__ WkT, float* __restrict__ kout) {
  __shared__ float xs[16][129];
  __shared__ float2 red[16][16];
  __shared__ float mrow[16], srow[16];
  int t = threadIdx.x;
  long long base = (long long)blockIdx.x * 16 * 128;
  const float4* in4 = (const float4*)(xin + base);
  for (int f = t; f < 512; f += 256) {
    float4 v = in4[f];
    int r = f >> 5, c = (f & 31) * 4;
    xs[r][c] = v.x; xs[r][c + 1] = v.y; xs[r][c + 2] = v.z; xs[r][c + 3] = v.w;
  }
  __syncthreads();
  {
    int row = t >> 4, l = t & 15;
    float s = 0.f, ss = 0.f;
    #pragma unroll
    for (int dd = 0; dd < 128; dd += 16) { float v = xs[row][dd + l]; s += v; ss = fmaf(v, v, ss); }
    red[row][l] = make_float2(s, ss);
  }
  __syncthreads();
  if (t < 16) {
    float s = 0.f, ss = 0.f;
    #pragma unroll
    for (int l = 0; l < 16; ++l) { float2 p = red[t][l]; s += p.x; ss += p.y; }
    float m = s * (1.0f / 128.0f);
    float var = ss * (1.0f / 128.0f) - m * m;
    mrow[t] = m;
    srow[t] = rsqrtf(var + 1e-5f);
  }
  __syncthreads();
  for (int f = t; f < 2048; f += 256) {
    int row = f >> 7, d = f & 127;
    xs[row][d] = (xs[row][d] - mrow[row]) * srow[row] * g[d] + bb[d];
  }
  __syncthreads();
  int j4 = t & 31, rg = t >> 5;
  int r0 = rg * 2;
  float a00 = 0, a01 = 0, a02 = 0, a03 = 0;
  float a10 = 0, a11 = 0, a12 = 0, a13 = 0;
  #pragma unroll 4
  for (int d = 0; d < 128; ++d) {
    float4 wv = *(const float4*)(WkT + d * 128 + j4 * 4);
    float x0 = xs[r0][d], x1 = xs[r0 + 1][d];
    a00 = fmaf(x0, wv.x, a00); a01 = fmaf(x0, wv.y, a01);
    a02 = fmaf(x0, wv.z, a02); a03 = fmaf(x0, wv.w, a03);
    a10 = fmaf(x1, wv.x, a10); a11 = fmaf(x1, wv.y, a11);
    a12 = fmaf(x1, wv.z, a12); a13 = fmaf(x1, wv.w, a13);
  }
  float* o0 = kout + base + (long long)r0 * 128 + j4 * 4;
  *(float4*)o0         = make_float4(a00, a01, a02, a03);
  *(float4*)(o0 + 128) = make_float4(a10, a11, a12, a13);
}

// ---------------------------------------------------------------------------
// S1 standalone (first iteration): LN(slots) -> mus, wA=iv, wB=-2*q*iv, cz=sum q^2*iv
__global__ __launch_bounds__(256) void s1_kernel(
    const float* __restrict__ slots, const float* __restrict__ g, const float* __restrict__ bb,
    const float* __restrict__ WqT, float* __restrict__ mus,
    float* __restrict__ wA, float* __restrict__ wB, float* __restrict__ cz) {
  __shared__ float sl[256];
  __shared__ float2 wr[4];
  __shared__ float qs_l[128], ivs_l[128];
  __shared__ float wrC[4];
  int t = threadIdx.x, bi = blockIdx.x;
  float v = slots[bi * 256 + t];
  float s = v, ss = v * v;
  #pragma unroll
  for (int o = 32; o > 0; o >>= 1) { s += __shfl_down(s, o); ss += __shfl_down(ss, o); }
  if ((t & 63) == 0) wr[t >> 6] = make_float2(s, ss);
  __syncthreads();
  float fs  = wr[0].x + wr[1].x + wr[2].x + wr[3].x;
  float fss = wr[0].y + wr[1].y + wr[2].y + wr[3].y;
  float m   = fs * (1.0f/256.0f);
  float var = fss * (1.0f/256.0f) - m * m;
  float isr = rsqrtf(var + 1e-5f);
  float sn  = (v - m) * isr * g[t] + bb[t];
  sl[t] = sn;
  __syncthreads();
  if (t < 128) {
    float acc = 0.f;
    #pragma unroll 4
    for (int d = 0; d < 128; ++d) acc = fmaf(sl[d], WqT[d * 128 + t], acc);
    qs_l[t] = acc;
    mus[bi * 128 + t] = sn;
  } else {
    int jj = t - 128;
    float acc = 0.f;
    #pragma unroll 4
    for (int d = 0; d < 128; ++d) acc = fmaf(sl[128 + d], WqT[d * 128 + jj], acc);
    ivs_l[jj] = expf(-2.0f * acc);
  }
  __syncthreads();
  float cp = 0.f;
  if (t < 128) {
    float iv = ivs_l[t], q = qs_l[t];
    wA[bi * 128 + t] = iv;
    wB[bi * 128 + t] = -2.0f * q * iv;
    cp = q * q * iv;
  }
  #pragma unroll
  for (int o = 32; o > 0; o >>= 1) cp += __shfl_down(cp, o);
  if ((t & 63) == 0) wrC[t >> 6] = cp;
  __syncthreads();
  if (t == 0) cz[bi] = wrC[0] + wrC[1];
}

// ---------------------------------------------------------------------------
// S2 v5: 64-n chunk, 512 thr, no k in LDS.
// phase1 2-n REGISTER BLOCKING: thread (w = t&15 granule-pair group,
// nt = t>>4 -> rows 2nt,2nt+1); each wa/wb granule read serves 2 rows
// (halves L1 W-traffic). k loads coalesced (16-lane 256B segments).
__global__ __launch_bounds__(512) void s2_kernel(
    const float* __restrict__ kmat, const float* __restrict__ wA,
    const float* __restrict__ wB,  const float* __restrict__ cz,
    const float* __restrict__ pi,
    float* __restrict__ wun, float* __restrict__ ws2, float* __restrict__ wden) {
  __shared__ float pdots[16][64][8];  // 32KB
  __shared__ float es[64][9];
  __shared__ float recip[64];
  __shared__ float gT[8][72];
  __shared__ float pd[8][8];
  __shared__ float pisl[8], czl[8];
  int t = threadIdx.x;
  int chunk = blockIdx.x, b = blockIdx.y;
  if (t < 8) { pisl[t] = pi[b * 8 + t]; czl[t] = cz[b * 8 + t]; }
  // ---- phase 1: thread (w = t&15, nt = t>>4 -> n0 = 2nt, n0+1)
  {
    int w = t & 15, nt = t >> 4;
    int n0 = nt * 2;
    const float4* kr4 = (const float4*)(kmat + (long long)(b * 2048 + chunk * 64) * 128);
    const float4* wa4 = (const float4*)(wA + b * 1024);
    const float4* wb4 = (const float4*)(wB + b * 1024);
    float acc0[8] = {0,0,0,0,0,0,0,0};
    float acc1[8] = {0,0,0,0,0,0,0,0};
    #pragma unroll
    for (int i = 0; i < 2; ++i) {
      int gg = i * 16 + w;
      float4 k0 = kr4[n0 * 32 + gg];
      float4 k1 = kr4[(n0 + 1) * 32 + gg];
      float x0 = k0.x * k0.x, y0 = k0.y * k0.y, z0 = k0.z * k0.z, w0 = k0.w * k0.w;
      float x1 = k1.x * k1.x, y1 = k1.y * k1.y, z1 = k1.z * k1.z, w1 = k1.w * k1.w;
      #pragma unroll
      for (int s = 0; s < 8; ++s) {
        float4 a4 = wa4[s * 32 + gg];
        float4 b4 = wb4[s * 32 + gg];
        float c0 = acc0[s], c1 = acc1[s];
        c0 = fmaf(x0, a4.x, c0); c0 = fmaf(k0.x, b4.x, c0);
        c0 = fmaf(y0, a4.y, c0); c0 = fmaf(k0.y, b4.y, c0);
        c0 = fmaf(z0, a4.z, c0); c0 = fmaf(k0.z, b4.z, c0);
        c0 = fmaf(w0, a4.w, c0); c0 = fmaf(k0.w, b4.w, c0);
        c1 = fmaf(x1, a4.x, c1); c1 = fmaf(k1.x, b4.x, c1);
        c1 = fmaf(y1, a4.y, c1); c1 = fmaf(k1.y, b4.y, c1);
        c1 = fmaf(z1, a4.z, c1); c1 = fmaf(k1.z, b4.z, c1);
        c1 = fmaf(w1, a4.w, c1); c1 = fmaf(k1.w, b4.w, c1);
        acc0[s] = c0; acc1[s] = c1;
      }
    }
    *(float4*)&pdots[w][n0][0]     = make_float4(acc0[0], acc0[1], acc0[2], acc0[3]);
    *(float4*)&pdots[w][n0][4]     = make_float4(acc0[4], acc0[5], acc0[6], acc0[7]);
    *(float4*)&pdots[w][n0 + 1][0] = make_float4(acc1[0], acc1[1], acc1[2], acc1[3]);
    *(float4*)&pdots[w][n0 + 1][4] = make_float4(acc1[4], acc1[5], acc1[6], acc1[7]);
  }
  __syncthreads();
  // ---- reduce over 16 w-groups + exp ; thread (n2 = t>>3, s = t&7)
  float e;
  {
    int n2 = t >> 3, s = t & 7;
    float dots = czl[s];
    #pragma unroll
    for (int w = 0; w < 16; ++w) dots += pdots[w][n2][s];
    e = (expf(-dots) + EPS_) * pisl[s];
    es[n2][s] = e;
  }
  __syncthreads();
  if (t < 64) {
    float ssum = 0.f;
    #pragma unroll
    for (int s = 0; s < 8; ++s) ssum += es[t][s];
    recip[t] = 1.0f / ssum;
  }
  __syncthreads();
  // ---- gammas + den partials
  {
    int n2 = t >> 3, s = t & 7;
    float gam = e * recip[n2];
    gT[s][n2] = gam;
    float p = gam;
    p += __shfl_down(p, 8); p += __shfl_down(p, 16); p += __shfl_down(p, 32);
    if ((t & 63) < 8) pd[t >> 6][t & 7] = p;
  }
  __syncthreads();
  if (t < 8) {
    float sden = 0.f;
    #pragma unroll
    for (int w = 0; w < 8; ++w) sden += pd[w][t];
    wden[(b * 32 + chunk) * 8 + t] = sden;
  }
  // ---- phase 2: thread (d = t&127, sh = t>>7 -> slots 2sh, 2sh+1)
  {
    int d = t & 127, sh = t >> 7;
    int s0 = sh * 2, s1 = s0 + 1;
    const float* kcol = kmat + (long long)(b * 2048 + chunk * 64) * 128 + d;
    float u0 = 0.f, u1 = 0.f, q0 = 0.f, q1 = 0.f;
    #pragma unroll 2
    for (int n3 = 0; n3 < 64; n3 += 4) {
      float4 ga = *(const float4*)&gT[s0][n3];
      float4 gb = *(const float4*)&gT[s1][n3];
      float k0 = kcol[(n3 + 0) * 128];
      float k1 = kcol[(n3 + 1) * 128];
      float k2 = kcol[(n3 + 2) * 128];
      float k3 = kcol[(n3 + 3) * 128];
      float k0s = k0 * k0, k1s = k1 * k1, k2s = k2 * k2, k3s = k3 * k3;
      u0 = fmaf(ga.x, k0, u0); q0 = fmaf(ga.x, k0s, q0);
      u1 = fmaf(gb.x, k0, u1); q1 = fmaf(gb.x, k0s, q1);
      u0 = fmaf(ga.y, k1, u0); q0 = fmaf(ga.y, k1s, q0);
      u1 = fmaf(gb.y, k1, u1); q1 = fmaf(gb.y, k1s, q1);
      u0 = fmaf(ga.z, k2, u0); q0 = fmaf(ga.z, k2s, q0);
      u1 = fmaf(gb.z, k2, u1); q1 = fmaf(gb.z, k2s, q1);
      u0 = fmaf(ga.w, k3, u0); q0 = fmaf(ga.w, k3s, q0);
      u1 = fmaf(gb.w, k3, u1); q1 = fmaf(gb.w, k3s, q1);
    }
    int pb = ((b * 32 + chunk) * 8) * 128 + d;
    wun[pb + s0 * 128] = u0; wun[pb + s1 * 128] = u1;
    ws2[pb + s0 * 128] = q0; ws2[pb + s1 * 128] = q1;
  }
}

// ---------------------------------------------------------------------------
// S3 fused: reduce(32 chunks) + GRU + LN + MLP + upd_ls + slots/pi; then
// next-iter S1 (emitting wA/wB/cz) or the final output MLP.
__global__ __launch_bounds__(512) void s3_kernel(
    const float* __restrict__ wun, const float* __restrict__ ws2, const float* __restrict__ wden,
    const float* __restrict__ WihT, const float* __restrict__ WhhT,
    const float* __restrict__ bih,  const float* __restrict__ bhh,
    const float* __restrict__ Wm1T, const float* __restrict__ bm1,
    const float* __restrict__ Wm2T, const float* __restrict__ bm2,
    const float* __restrict__ gmu,  const float* __restrict__ bmu,
    float* __restrict__ slots, float* __restrict__ pi,
    int do_s1,
    const float* __restrict__ gs, const float* __restrict__ bs,
    const float* __restrict__ WqT,
    float* __restrict__ mus, float* __restrict__ wAo, float* __restrict__ wBo,
    float* __restrict__ czo,
    const float* __restrict__ Wo1T, const float* __restrict__ bo1,
    const float* __restrict__ Wo2T, const float* __restrict__ bo2,
    float* __restrict__ out) {
  int t = threadIdx.x, bi = blockIdx.x;
  int d = t & 127, q = t >> 7;      // q in [0,4)
  int b = bi >> 3, i = bi & 7;
  __shared__ float redU[4][128], redS[4][128];
  __shared__ float dred[32];
  __shared__ float xs[128], hs[128];
  __shared__ float gacc[4][6][128];
  __shared__ float ga[6][128];
  __shared__ float grus[128], hl[128], m1s[128];
  __shared__ float macc[4][128];
  __shared__ float2 wr2[2];
  __shared__ float uarr[256];
  float unp = 0.f, s2p = 0.f;
  #pragma unroll
  for (int c = q * 8; c < q * 8 + 8; ++c) {
    int po = ((b * 32 + c) * 8 + i) * 128 + d;
    unp += wun[po]; s2p += ws2[po];
  }
  redU[q][d] = unp; redS[q][d] = s2p;
  if (t < 32) dred[t] = wden[(b * 32 + t) * 8 + i];
  if (q == 1) hs[d] = mus[bi * 128 + d];
  __syncthreads();
  float den = 0.f;
  #pragma unroll
  for (int c = 0; c < 32; ++c) den += dred[c];
  float un  = redU[0][d] + redU[1][d] + redU[2][d] + redU[3][d];
  float s2v = redS[0][d] + redS[1][d] + redS[2][d] + redS[3][d];
  if (q == 0) xs[d] = un / den;
  __syncthreads();
  {
    float a0 = 0, a1 = 0, a2 = 0, a3 = 0, a4 = 0, a5 = 0;
    #pragma unroll 4
    for (int dd = q * 32; dd < q * 32 + 32; ++dd) {
      float xv = xs[dd], hv = hs[dd];
      const float* wi = &WihT[dd * 384 + d];
      const float* wh = &WhhT[dd * 384 + d];
      a0 = fmaf(xv, wi[0],   a0);
      a1 = fmaf(xv, wi[128], a1);
      a2 = fmaf(xv, wi[256], a2);
      a3 = fmaf(hv, wh[0],   a3);
      a4 = fmaf(hv, wh[128], a4);
      a5 = fmaf(hv, wh[256], a5);
    }
    gacc[q][0][d] = a0; gacc[q][1][d] = a1; gacc[q][2][d] = a2;
    gacc[q][3][d] = a3; gacc[q][4][d] = a4; gacc[q][5][d] = a5;
  }
  __syncthreads();
  for (int f = t; f < 768; f += 512) {
    int j = f >> 7, dd = f & 127;
    ga[j][dd] = gacc[0][j][dd] + gacc[1][j][dd] + gacc[2][j][dd] + gacc[3][j][dd];
  }
  __syncthreads();
  float gru = 0.f;
  if (q == 0) {
    float ir = ga[0][d] + bih[d], iz = ga[1][d] + bih[128 + d], inn = ga[2][d] + bih[256 + d];
    float hr = ga[3][d] + bhh[d], hz = ga[4][d] + bhh[128 + d], hn  = ga[5][d] + bhh[256 + d];
    float r  = 1.0f / (1.0f + expf(-(ir + hr)));
    float z  = 1.0f / (1.0f + expf(-(iz + hz)));
    float nn = tanhf(inn + r * hn);
    gru = (1.0f - z) * nn + z * hs[d];
    grus[d] = gru;
    float s = gru, ssq = gru * gru;
    #pragma unroll
    for (int o = 32; o > 0; o >>= 1) { s += __shfl_down(s, o); ssq += __shfl_down(ssq, o); }
    if ((d & 63) == 0) wr2[d >> 6] = make_float2(s, ssq);
  }
  __syncthreads();
  if (q == 0) {
    float fs = wr2[0].x + wr2[1].x, fss = wr2[0].y + wr2[1].y;
    float mean = fs * (1.0f/128.0f);
    float var  = fss * (1.0f/128.0f) - mean * mean;
    hl[d] = (gru - mean) * rsqrtf(var + 1e-5f) * gmu[d] + bmu[d];
  }
  __syncthreads();
  {
    float m1p = 0.f;
    #pragma unroll 4
    for (int dd = q * 32; dd < q * 32 + 32; ++dd)
      m1p = fmaf(hl[dd], Wm1T[dd * 128 + d], m1p);
    macc[q][d] = m1p;
  }
  __syncthreads();
  if (q == 0) m1s[d] = fmaxf(macc[0][d] + macc[1][d] + macc[2][d] + macc[3][d] + bm1[d], 0.f);
  __syncthreads();
  {
    float m2p = 0.f;
    #pragma unroll 4
    for (int dd = q * 32; dd < q * 32 + 32; ++dd)
      m2p = fmaf(m1s[dd], Wm2T[dd * 128 + d], m2p);
    macc[q][d] = m2p;
  }
  __syncthreads();
  if (q == 0) {
    float u = grus[d] + macc[0][d] + macc[1][d] + macc[2][d] + macc[3][d] + bm2[d];
    float val = (s2v - 2.0f * u * un + u * u * den) / den;
    float ls = 0.5f * logf(fmaxf(val, 0.0f) + EPS_);
    slots[bi * 256 + d]       = u;
    slots[bi * 256 + 128 + d] = ls;
    uarr[d] = u; uarr[128 + d] = ls;
    if (d == 0) pi[bi] = den;
  }
  __syncthreads();
  if (do_s1) {
    __shared__ float2 wr4[4];
    __shared__ float sln[256];
    __shared__ float qacc[2][2][128];
    __shared__ float qs_l[128], ivs_l[128];
    __shared__ float wrC[8];
    if (t < 256) {
      float v2 = uarr[t];
      float s = v2, ssq = v2 * v2;
      #pragma unroll
      for (int o = 32; o > 0; o >>= 1) { s += __shfl_down(s, o); ssq += __shfl_down(ssq, o); }
      if ((t & 63) == 0) wr4[t >> 6] = make_float2(s, ssq);
    }
    __syncthreads();
    if (t < 256) {
      float fs  = wr4[0].x + wr4[1].x + wr4[2].x + wr4[3].x;
      float fss = wr4[0].y + wr4[1].y + wr4[2].y + wr4[3].y;
      float m   = fs * (1.0f/256.0f);
      float var = fss * (1.0f/256.0f) - m * m;
      sln[t] = (uarr[t] - m) * rsqrtf(var + 1e-5f) * gs[t] + bs[t];
    }
    __syncthreads();
    {
      int h2 = t >> 8, qq = (t >> 7) & 1, d2 = t & 127;
      const float* src = sln + h2 * 128;
      float acc = 0.f;
      #pragma unroll 4
      for (int dd = qq * 64; dd < qq * 64 + 64; ++dd)
        acc = fmaf(src[dd], WqT[dd * 128 + d2], acc);
      qacc[h2][qq][d2] = acc;
    }
    __syncthreads();
    if (t < 128) {
      qs_l[t] = qacc[0][0][t] + qacc[0][1][t];
      mus[bi * 128 + t] = sln[t];
    } else if (t < 256) {
      int dd2 = t - 128;
      ivs_l[dd2] = expf(-2.0f * (qacc[1][0][dd2] + qacc[1][1][dd2]));
    }
    __syncthreads();
    float cp = 0.f;
    if (t < 128) {
      float iv = ivs_l[t], qv = qs_l[t];
      wAo[bi * 128 + t] = iv;
      wBo[bi * 128 + t] = -2.0f * qv * iv;
      cp = qv * qv * iv;
    }
    #pragma unroll
    for (int o = 32; o > 0; o >>= 1) cp += __shfl_down(cp, o);
    if ((t & 63) == 0) wrC[t >> 6] = cp;
    __syncthreads();
    if (t == 0) czo[bi] = wrC[0] + wrC[1];
  } else {
    __shared__ float oacc[2][256];
    __shared__ float hh[256];
    {
      int o = t & 255, qq = t >> 8;
      float acc = 0.f;
      #pragma unroll 4
      for (int dd = qq * 128; dd < qq * 128 + 128; ++dd)
        acc = fmaf(uarr[dd], Wo1T[dd * 256 + o], acc);
      oacc[qq][o] = acc;
    }
    __syncthreads();
    if (t < 256) hh[t] = fmaxf(oacc[0][t] + oacc[1][t] + bo1[t], 0.f);
    __syncthreads();
    {
      int o2 = t & 127, q4 = t >> 7;
      float acc2 = 0.f;
      #pragma unroll 4
      for (int dd = q4 * 64; dd < q4 * 64 + 64; ++dd)
        acc2 = fmaf(hh[dd], Wo2T[dd * 128 + o2], acc2);
      macc[q4][o2] = acc2;
    }
    __syncthreads();
    if (t < 128) out[bi * 128 + t] = macc[0][t] + macc[1][t] + macc[2][t] + macc[3][t] + bo2[t];
  }
}

// ---------------------------------------------------------------------------
extern "C" void kernel_launch(void* const* d_in, const int* in_sizes, int n_in,
                              void* d_out, int out_size, void* d_ws, size_t ws_size,
                              hipStream_t stream) {
  const float* inputs = (const float*)d_in[0];
  const float* noise  = (const float*)d_in[1];
  const float* smu    = (const float*)d_in[2];
  const float* sls    = (const float*)d_in[3];
  const float* Wq     = (const float*)d_in[4];
  const float* Wk     = (const float*)d_in[5];
  const float* Wih    = (const float*)d_in[6];
  const float* Whh    = (const float*)d_in[7];
  const float* bih    = (const float*)d_in[8];
  const float* bhh    = (const float*)d_in[9];
  const float* Wm1    = (const float*)d_in[10];
  const float* bm1    = (const float*)d_in[11];
  const float* Wm2    = (const float*)d_in[12];
  const float* bm2    = (const float*)d_in[13];
  const float* gin    = (const float*)d_in[14];
  const float* bin    = (const float*)d_in[15];
  const float* gsl    = (const float*)d_in[16];
  const float* bsl    = (const float*)d_in[17];
  const float* gmu    = (const float*)d_in[18];
  const float* bmu    = (const float*)d_in[19];
  const float* Wo1    = (const float*)d_in[20];
  const float* bo1    = (const float*)d_in[21];
  const float* Wo2    = (const float*)d_in[22];
  const float* bo2    = (const float*)d_in[23];

  float* ws    = (float*)d_ws;
  float* kbuf  = ws + OFF_K;
  float* WqT   = ws + OFF_WQT;
  float* WkT   = ws + OFF_WKT;
  float* WihT  = ws + OFF_WIHT;
  float* WhhT  = ws + OFF_WHHT;
  float* Wm1T  = ws + OFF_WM1T;
  float* Wm2T  = ws + OFF_WM2T;
  float* Wo1T  = ws + OFF_WO1T;
  float* Wo2T  = ws + OFF_WO2T;
  float* slots = ws + OFF_SLOTS;
  float* pibuf = ws + OFF_PI;
  float* mus   = ws + OFF_MUS;
  float* wA    = ws + OFF_WA;
  float* wB    = ws + OFF_WB;
  float* wun   = ws + OFF_UN;
  float* ws2   = ws + OFF_S2;
  float* wden  = ws + OFF_DEN;
  float* czb   = ws + OFF_CZ;

  hipLaunchKernelGGL(init_kernel, dim3(1153), dim3(256), 0, stream,
                     Wq, Wk, Wih, Whh, Wm1, Wm2, Wo1, Wo2, smu, sls, noise, ws);
  hipLaunchKernelGGL(k_kernel, dim3(2048), dim3(256), 0, stream,
                     inputs, gin, bin, WkT, kbuf);
  hipLaunchKernelGGL(s1_kernel, dim3(128), dim3(256), 0, stream,
                     slots, gsl, bsl, WqT, mus, wA, wB, czb);
  for (int s = 0; s < 4; ++s) {
    hipLaunchKernelGGL(s2_kernel, dim3(32, 16), dim3(512), 0, stream,
                       kbuf, wA, wB, czb, pibuf, wun, ws2, wden);
    hipLaunchKernelGGL(s3_kernel, dim3(128), dim3(512), 0, stream,
                       wun, ws2, wden, WihT, WhhT, bih, bhh,
                       Wm1T, bm1, Wm2T, bm2, gmu, bmu, slots, pibuf,
                       (s < 3) ? 1 : 0, gsl, bsl, WqT, mus, wA, wB, czb,
                       Wo1T, bo1, Wo2T, bo2, (float*)d_out);
  }
}

// Round 9
// 176.233 us; speedup vs baseline: 4.6590x; 1.0112x over previous
//
#include <hip/hip_runtime.h>

#define EPS_ 1e-8f

// sizes: B=16, N=2048, D=128, NS=8, H=128, steps=4
constexpr int OFF_K     = 0;                       // 16*2048*128 = 4194304
constexpr int OFF_WQT   = 4194304;                 // 16384
constexpr int OFF_WKT   = OFF_WQT  + 16384;
constexpr int OFF_WIHT  = OFF_WKT  + 16384;        // 49152
constexpr int OFF_WHHT  = OFF_WIHT + 49152;        // 49152
constexpr int OFF_WM1T  = OFF_WHHT + 49152;        // 16384
constexpr int OFF_WM2T  = OFF_WM1T + 16384;        // 16384
constexpr int OFF_WO1T  = OFF_WM2T + 16384;        // 65536
constexpr int OFF_WO2T  = OFF_WO1T + 65536;        // 32768
constexpr int OFF_SLOTS = OFF_WO2T + 32768;        // 32768
constexpr int OFF_PI    = OFF_SLOTS+ 32768;        // 128
constexpr int OFF_MUS   = OFF_PI   + 128;          // 16384
constexpr int OFF_WA    = OFF_MUS  + 16384;        // 16384 (iv)
constexpr int OFF_WB    = OFF_WA   + 16384;        // 16384 (-2*q*iv)
constexpr int OFF_UN    = OFF_WB   + 16384;        // 16*32*8*128 = 524288
constexpr int OFF_S2    = OFF_UN   + 524288;       // 524288
constexpr int OFF_DEN   = OFF_S2   + 524288;       // 16*32*8 = 4096
constexpr int OFF_CZ    = OFF_DEN  + 4096;         // 128

// ---------------------------------------------------------------------------
__global__ __launch_bounds__(256) void init_kernel(
    const float* __restrict__ Wq,  const float* __restrict__ Wk,
    const float* __restrict__ Wih, const float* __restrict__ Whh,
    const float* __restrict__ Wm1, const float* __restrict__ Wm2,
    const float* __restrict__ Wo1, const float* __restrict__ Wo2,
    const float* __restrict__ smu, const float* __restrict__ sls,
    const float* __restrict__ noise, float* __restrict__ ws) {
  int idx = blockIdx.x * 256 + threadIdx.x;
  if (idx < 16384) { int j = idx >> 7, d = idx & 127; ws[OFF_WQT + d*128 + j] = Wq[idx]; return; }
  idx -= 16384;
  if (idx < 16384) { int j = idx >> 7, d = idx & 127; ws[OFF_WKT + d*128 + j] = Wk[idx]; return; }
  idx -= 16384;
  if (idx < 49152) { int j = idx >> 7, d = idx & 127; ws[OFF_WIHT + d*384 + j] = Wih[idx]; return; }
  idx -= 49152;
  if (idx < 49152) { int j = idx >> 7, d = idx & 127; ws[OFF_WHHT + d*384 + j] = Whh[idx]; return; }
  idx -= 49152;
  if (idx < 16384) { int j = idx >> 7, d = idx & 127; ws[OFF_WM1T + d*128 + j] = Wm1[idx]; return; }
  idx -= 16384;
  if (idx < 16384) { int j = idx >> 7, d = idx & 127; ws[OFF_WM2T + d*128 + j] = Wm2[idx]; return; }
  idx -= 16384;
  if (idx < 65536) { int j = idx >> 8, d = idx & 255; ws[OFF_WO1T + d*256 + j] = Wo1[idx]; return; }
  idx -= 65536;
  if (idx < 32768) { int j = idx >> 8, m = idx & 255; ws[OFF_WO2T + m*128 + j] = Wo2[idx]; return; }
  idx -= 32768;
  if (idx < 32768) { int c = idx & 255; ws[OFF_SLOTS + idx] = smu[c] + expf(sls[c]) * noise[idx]; return; }
  idx -= 32768;
  if (idx < 128) { ws[OFF_PI + idx] = 0.125f; }
}

// ---------------------------------------------------------------------------
// k = LN(inputs) @ Wk.T : 64 rows/block, 512 blocks, 256 thr.
// LN in registers; x written TRANSPOSED xsT[d][r] (pad 72).
// GEMM per thread: R=8 rows x J=4 cols; per d: 1 coalesced b128 W load +
// 2 broadcast b128 xsT reads + 32 FMA. W-bytes/output = 64 (was 256).
__global__ __launch_bounds__(256) void k_kernel(
    const float* __restrict__ xin, const float* __restrict__ g, const float* __restrict__ bb,
    const float* __restrict__ WkT, float* __restrict__ kout) {
  __shared__ float xsT[128][72];     // 36.9KB, d-major
  __shared__ float2 red2[64][4];
  __shared__ float mrow[64], srow[64];
  int t = threadIdx.x;
  long long base = (long long)blockIdx.x * 64 * 128;
  int r = t >> 2, q = t & 3;         // row 0..63, quarter 0..3
  float vals[32];
  {
    const float4* src = (const float4*)(xin + base + r * 128 + q * 32);
    #pragma unroll
    for (int i = 0; i < 8; ++i) *(float4*)&vals[i * 4] = src[i];
  }
  {
    float s = 0.f, ss = 0.f;
    #pragma unroll
    for (int i = 0; i < 32; ++i) { float v = vals[i]; s += v; ss = fmaf(v, v, ss); }
    red2[r][q] = make_float2(s, ss);
  }
  __syncthreads();
  if (t < 64) {
    float s = 0.f, ss = 0.f;
    #pragma unroll
    for (int c = 0; c < 4; ++c) { float2 p = red2[t][c]; s += p.x; ss += p.y; }
    float m = s * (1.0f / 128.0f);
    float var = ss * (1.0f / 128.0f) - m * m;
    mrow[t] = m; srow[t] = rsqrtf(var + 1e-5f);
  }
  __syncthreads();
  {
    float m = mrow[r], is = srow[r];
    #pragma unroll 8
    for (int u = 0; u < 32; ++u) {
      int d = q * 32 + u;
      xsT[d][r] = (vals[u] - m) * is * g[d] + bb[d];
    }
  }
  __syncthreads();
  // GEMM: j4 = t&31 -> cols j4*4..+3 ; rg = t>>5 -> rows rg*8..+7
  int j4 = t & 31, rg = t >> 5;
  int r0 = rg * 8;
  float a0[8], a1[8], a2[8], a3[8];   // a{c}[row]: col j4*4+c
  #pragma unroll
  for (int i = 0; i < 8; ++i) { a0[i] = 0.f; a1[i] = 0.f; a2[i] = 0.f; a3[i] = 0.f; }
  #pragma unroll 2
  for (int d = 0; d < 128; ++d) {
    float4 wv = *(const float4*)(WkT + d * 128 + j4 * 4);
    float4 x0 = *(const float4*)&xsT[d][r0];
    float4 x1 = *(const float4*)&xsT[d][r0 + 4];
    a0[0] = fmaf(x0.x, wv.x, a0[0]); a1[0] = fmaf(x0.x, wv.y, a1[0]);
    a2[0] = fmaf(x0.x, wv.z, a2[0]); a3[0] = fmaf(x0.x, wv.w, a3[0]);
    a0[1] = fmaf(x0.y, wv.x, a0[1]); a1[1] = fmaf(x0.y, wv.y, a1[1]);
    a2[1] = fmaf(x0.y, wv.z, a2[1]); a3[1] = fmaf(x0.y, wv.w, a3[1]);
    a0[2] = fmaf(x0.z, wv.x, a0[2]); a1[2] = fmaf(x0.z, wv.y, a1[2]);
    a2[2] = fmaf(x0.z, wv.z, a2[2]); a3[2] = fmaf(x0.z, wv.w, a3[2]);
    a0[3] = fmaf(x0.w, wv.x, a0[3]); a1[3] = fmaf(x0.w, wv.y, a1[3]);
    a2[3] = fmaf(x0.w, wv.z, a2[3]); a3[3] = fmaf(x0.w, wv.w, a3[3]);
    a0[4] = fmaf(x1.x, wv.x, a0[4]); a1[4] = fmaf(x1.x, wv.y, a1[4]);
    a2[4] = fmaf(x1.x, wv.z, a2[4]); a3[4] = fmaf(x1.x, wv.w, a3[4]);
    a0[5] = fmaf(x1.y, wv.x, a0[5]); a1[5] = fmaf(x1.y, wv.y, a1[5]);
    a2[5] = fmaf(x1.y, wv.z, a2[5]); a3[5] = fmaf(x1.y, wv.w, a3[5]);
    a0[6] = fmaf(x1.z, wv.x, a0[6]); a1[6] = fmaf(x1.z, wv.y, a1[6]);
    a2[6] = fmaf(x1.z, wv.z, a2[6]); a3[6] = fmaf(x1.z, wv.w, a3[6]);
    a0[7] = fmaf(x1.w, wv.x, a0[7]); a1[7] = fmaf(x1.w, wv.y, a1[7]);
    a2[7] = fmaf(x1.w, wv.z, a2[7]); a3[7] = fmaf(x1.w, wv.w, a3[7]);
  }
  #pragma unroll
  for (int i = 0; i < 8; ++i) {
    float* o = kout + base + (long long)(r0 + i) * 128 + j4 * 4;
    *(float4*)o = make_float4(a0[i], a1[i], a2[i], a3[i]);
  }
}

// ---------------------------------------------------------------------------
// S1 standalone (first iteration): LN(slots) -> mus, wA=iv, wB=-2*q*iv, cz=sum q^2*iv
__global__ __launch_bounds__(256) void s1_kernel(
    const float* __restrict__ slots, const float* __restrict__ g, const float* __restrict__ bb,
    const float* __restrict__ WqT, float* __restrict__ mus,
    float* __restrict__ wA, float* __restrict__ wB, float* __restrict__ cz) {
  __shared__ float sl[256];
  __shared__ float2 wr[4];
  __shared__ float qs_l[128], ivs_l[128];
  __shared__ float wrC[4];
  int t = threadIdx.x, bi = blockIdx.x;
  float v = slots[bi * 256 + t];
  float s = v, ss = v * v;
  #pragma unroll
  for (int o = 32; o > 0; o >>= 1) { s += __shfl_down(s, o); ss += __shfl_down(ss, o); }
  if ((t & 63) == 0) wr[t >> 6] = make_float2(s, ss);
  __syncthreads();
  float fs  = wr[0].x + wr[1].x + wr[2].x + wr[3].x;
  float fss = wr[0].y + wr[1].y + wr[2].y + wr[3].y;
  float m   = fs * (1.0f/256.0f);
  float var = fss * (1.0f/256.0f) - m * m;
  float isr = rsqrtf(var + 1e-5f);
  float sn  = (v - m) * isr * g[t] + bb[t];
  sl[t] = sn;
  __syncthreads();
  if (t < 128) {
    float acc = 0.f;
    #pragma unroll 4
    for (int d = 0; d < 128; ++d) acc = fmaf(sl[d], WqT[d * 128 + t], acc);
    qs_l[t] = acc;
    mus[bi * 128 + t] = sn;
  } else {
    int jj = t - 128;
    float acc = 0.f;
    #pragma unroll 4
    for (int d = 0; d < 128; ++d) acc = fmaf(sl[128 + d], WqT[d * 128 + jj], acc);
    ivs_l[jj] = expf(-2.0f * acc);
  }
  __syncthreads();
  float cp = 0.f;
  if (t < 128) {
    float iv = ivs_l[t], q = qs_l[t];
    wA[bi * 128 + t] = iv;
    wB[bi * 128 + t] = -2.0f * q * iv;
    cp = q * q * iv;
  }
  #pragma unroll
  for (int o = 32; o > 0; o >>= 1) cp += __shfl_down(cp, o);
  if ((t & 63) == 0) wrC[t >> 6] = cp;
  __syncthreads();
  if (t == 0) cz[bi] = wrC[0] + wrC[1];
}

// ---------------------------------------------------------------------------
// S2 v5: 64-n chunk, 512 thr, no k in LDS.  (unchanged from round 8)
__global__ __launch_bounds__(512) void s2_kernel(
    const float* __restrict__ kmat, const float* __restrict__ wA,
    const float* __restrict__ wB,  const float* __restrict__ cz,
    const float* __restrict__ pi,
    float* __restrict__ wun, float* __restrict__ ws2, float* __restrict__ wden) {
  __shared__ float pdots[16][64][8];  // 32KB
  __shared__ float es[64][9];
  __shared__ float recip[64];
  __shared__ float gT[8][72];
  __shared__ float pd[8][8];
  __shared__ float pisl[8], czl[8];
  int t = threadIdx.x;
  int chunk = blockIdx.x, b = blockIdx.y;
  if (t < 8) { pisl[t] = pi[b * 8 + t]; czl[t] = cz[b * 8 + t]; }
  // ---- phase 1: thread (w = t&15, nt = t>>4 -> n0 = 2nt, n0+1)
  {
    int w = t & 15, nt = t >> 4;
    int n0 = nt * 2;
    const float4* kr4 = (const float4*)(kmat + (long long)(b * 2048 + chunk * 64) * 128);
    const float4* wa4 = (const float4*)(wA + b * 1024);
    const float4* wb4 = (const float4*)(wB + b * 1024);
    float acc0[8] = {0,0,0,0,0,0,0,0};
    float acc1[8] = {0,0,0,0,0,0,0,0};
    #pragma unroll
    for (int i = 0; i < 2; ++i) {
      int gg = i * 16 + w;
      float4 k0 = kr4[n0 * 32 + gg];
      float4 k1 = kr4[(n0 + 1) * 32 + gg];
      float x0 = k0.x * k0.x, y0 = k0.y * k0.y, z0 = k0.z * k0.z, w0 = k0.w * k0.w;
      float x1 = k1.x * k1.x, y1 = k1.y * k1.y, z1 = k1.z * k1.z, w1 = k1.w * k1.w;
      #pragma unroll
      for (int s = 0; s < 8; ++s) {
        float4 a4 = wa4[s * 32 + gg];
        float4 b4 = wb4[s * 32 + gg];
        float c0 = acc0[s], c1 = acc1[s];
        c0 = fmaf(x0, a4.x, c0); c0 = fmaf(k0.x, b4.x, c0);
        c0 = fmaf(y0, a4.y, c0); c0 = fmaf(k0.y, b4.y, c0);
        c0 = fmaf(z0, a4.z, c0); c0 = fmaf(k0.z, b4.z, c0);
        c0 = fmaf(w0, a4.w, c0); c0 = fmaf(k0.w, b4.w, c0);
        c1 = fmaf(x1, a4.x, c1); c1 = fmaf(k1.x, b4.x, c1);
        c1 = fmaf(y1, a4.y, c1); c1 = fmaf(k1.y, b4.y, c1);
        c1 = fmaf(z1, a4.z, c1); c1 = fmaf(k1.z, b4.z, c1);
        c1 = fmaf(w1, a4.w, c1); c1 = fmaf(k1.w, b4.w, c1);
        acc0[s] = c0; acc1[s] = c1;
      }
    }
    *(float4*)&pdots[w][n0][0]     = make_float4(acc0[0], acc0[1], acc0[2], acc0[3]);
    *(float4*)&pdots[w][n0][4]     = make_float4(acc0[4], acc0[5], acc0[6], acc0[7]);
    *(float4*)&pdots[w][n0 + 1][0] = make_float4(acc1[0], acc1[1], acc1[2], acc1[3]);
    *(float4*)&pdots[w][n0 + 1][4] = make_float4(acc1[4], acc1[5], acc1[6], acc1[7]);
  }
  __syncthreads();
  float e;
  {
    int n2 = t >> 3, s = t & 7;
    float dots = czl[s];
    #pragma unroll
    for (int w = 0; w < 16; ++w) dots += pdots[w][n2][s];
    e = (expf(-dots) + EPS_) * pisl[s];
    es[n2][s] = e;
  }
  __syncthreads();
  if (t < 64) {
    float ssum = 0.f;
    #pragma unroll
    for (int s = 0; s < 8; ++s) ssum += es[t][s];
    recip[t] = 1.0f / ssum;
  }
  __syncthreads();
  {
    int n2 = t >> 3, s = t & 7;
    float gam = e * recip[n2];
    gT[s][n2] = gam;
    float p = gam;
    p += __shfl_down(p, 8); p += __shfl_down(p, 16); p += __shfl_down(p, 32);
    if ((t & 63) < 8) pd[t >> 6][t & 7] = p;
  }
  __syncthreads();
  if (t < 8) {
    float sden = 0.f;
    #pragma unroll
    for (int w = 0; w < 8; ++w) sden += pd[w][t];
    wden[(b * 32 + chunk) * 8 + t] = sden;
  }
  {
    int d = t & 127, sh = t >> 7;
    int s0 = sh * 2, s1 = s0 + 1;
    const float* kcol = kmat + (long long)(b * 2048 + chunk * 64) * 128 + d;
    float u0 = 0.f, u1 = 0.f, q0 = 0.f, q1 = 0.f;
    #pragma unroll 2
    for (int n3 = 0; n3 < 64; n3 += 4) {
      float4 ga = *(const float4*)&gT[s0][n3];
      float4 gb = *(const float4*)&gT[s1][n3];
      float k0 = kcol[(n3 + 0) * 128];
      float k1 = kcol[(n3 + 1) * 128];
      float k2 = kcol[(n3 + 2) * 128];
      float k3 = kcol[(n3 + 3) * 128];
      float k0s = k0 * k0, k1s = k1 * k1, k2s = k2 * k2, k3s = k3 * k3;
      u0 = fmaf(ga.x, k0, u0); q0 = fmaf(ga.x, k0s, q0);
      u1 = fmaf(gb.x, k0, u1); q1 = fmaf(gb.x, k0s, q1);
      u0 = fmaf(ga.y, k1, u0); q0 = fmaf(ga.y, k1s, q0);
      u1 = fmaf(gb.y, k1, u1); q1 = fmaf(gb.y, k1s, q1);
      u0 = fmaf(ga.z, k2, u0); q0 = fmaf(ga.z, k2s, q0);
      u1 = fmaf(gb.z, k2, u1); q1 = fmaf(gb.z, k2s, q1);
      u0 = fmaf(ga.w, k3, u0); q0 = fmaf(ga.w, k3s, q0);
      u1 = fmaf(gb.w, k3, u1); q1 = fmaf(gb.w, k3s, q1);
    }
    int pb = ((b * 32 + chunk) * 8) * 128 + d;
    wun[pb + s0 * 128] = u0; wun[pb + s1 * 128] = u1;
    ws2[pb + s0 * 128] = q0; ws2[pb + s1 * 128] = q1;
  }
}

// ---------------------------------------------------------------------------
// S3 fused: reduce(32 chunks) + GRU + LN + MLP + upd_ls + slots/pi; then
// next-iter S1 (emitting wA/wB/cz) or the final output MLP.  (unchanged)
__global__ __launch_bounds__(512) void s3_kernel(
    const float* __restrict__ wun, const float* __restrict__ ws2, const float* __restrict__ wden,
    const float* __restrict__ WihT, const float* __restrict__ WhhT,
    const float* __restrict__ bih,  const float* __restrict__ bhh,
    const float* __restrict__ Wm1T, const float* __restrict__ bm1,
    const float* __restrict__ Wm2T, const float* __restrict__ bm2,
    const float* __restrict__ gmu,  const float* __restrict__ bmu,
    float* __restrict__ slots, float* __restrict__ pi,
    int do_s1,
    const float* __restrict__ gs, const float* __restrict__ bs,
    const float* __restrict__ WqT,
    float* __restrict__ mus, float* __restrict__ wAo, float* __restrict__ wBo,
    float* __restrict__ czo,
    const float* __restrict__ Wo1T, const float* __restrict__ bo1,
    const float* __restrict__ Wo2T, const float* __restrict__ bo2,
    float* __restrict__ out) {
  int t = threadIdx.x, bi = blockIdx.x;
  int d = t & 127, q = t >> 7;      // q in [0,4)
  int b = bi >> 3, i = bi & 7;
  __shared__ float redU[4][128], redS[4][128];
  __shared__ float dred[32];
  __shared__ float xs[128], hs[128];
  __shared__ float gacc[4][6][128];
  __shared__ float ga[6][128];
  __shared__ float grus[128], hl[128], m1s[128];
  __shared__ float macc[4][128];
  __shared__ float2 wr2[2];
  __shared__ float uarr[256];
  float unp = 0.f, s2p = 0.f;
  #pragma unroll
  for (int c = q * 8; c < q * 8 + 8; ++c) {
    int po = ((b * 32 + c) * 8 + i) * 128 + d;
    unp += wun[po]; s2p += ws2[po];
  }
  redU[q][d] = unp; redS[q][d] = s2p;
  if (t < 32) dred[t] = wden[(b * 32 + t) * 8 + i];
  if (q == 1) hs[d] = mus[bi * 128 + d];
  __syncthreads();
  float den = 0.f;
  #pragma unroll
  for (int c = 0; c < 32; ++c) den += dred[c];
  float un  = redU[0][d] + redU[1][d] + redU[2][d] + redU[3][d];
  float s2v = redS[0][d] + redS[1][d] + redS[2][d] + redS[3][d];
  if (q == 0) xs[d] = un / den;
  __syncthreads();
  {
    float a0 = 0, a1 = 0, a2 = 0, a3 = 0, a4 = 0, a5 = 0;
    #pragma unroll 4
    for (int dd = q * 32; dd < q * 32 + 32; ++dd) {
      float xv = xs[dd], hv = hs[dd];
      const float* wi = &WihT[dd * 384 + d];
      const float* wh = &WhhT[dd * 384 + d];
      a0 = fmaf(xv, wi[0],   a0);
      a1 = fmaf(xv, wi[128], a1);
      a2 = fmaf(xv, wi[256], a2);
      a3 = fmaf(hv, wh[0],   a3);
      a4 = fmaf(hv, wh[128], a4);
      a5 = fmaf(hv, wh[256], a5);
    }
    gacc[q][0][d] = a0; gacc[q][1][d] = a1; gacc[q][2][d] = a2;
    gacc[q][3][d] = a3; gacc[q][4][d] = a4; gacc[q][5][d] = a5;
  }
  __syncthreads();
  for (int f = t; f < 768; f += 512) {
    int j = f >> 7, dd = f & 127;
    ga[j][dd] = gacc[0][j][dd] + gacc[1][j][dd] + gacc[2][j][dd] + gacc[3][j][dd];
  }
  __syncthreads();
  float gru = 0.f;
  if (q == 0) {
    float ir = ga[0][d] + bih[d], iz = ga[1][d] + bih[128 + d], inn = ga[2][d] + bih[256 + d];
    float hr = ga[3][d] + bhh[d], hz = ga[4][d] + bhh[128 + d], hn  = ga[5][d] + bhh[256 + d];
    float r  = 1.0f / (1.0f + expf(-(ir + hr)));
    float z  = 1.0f / (1.0f + expf(-(iz + hz)));
    float nn = tanhf(inn + r * hn);
    gru = (1.0f - z) * nn + z * hs[d];
    grus[d] = gru;
    float s = gru, ssq = gru * gru;
    #pragma unroll
    for (int o = 32; o > 0; o >>= 1) { s += __shfl_down(s, o); ssq += __shfl_down(ssq, o); }
    if ((d & 63) == 0) wr2[d >> 6] = make_float2(s, ssq);
  }
  __syncthreads();
  if (q == 0) {
    float fs = wr2[0].x + wr2[1].x, fss = wr2[0].y + wr2[1].y;
    float mean = fs * (1.0f/128.0f);
    float var  = fss * (1.0f/128.0f) - mean * mean;
    hl[d] = (gru - mean) * rsqrtf(var + 1e-5f) * gmu[d] + bmu[d];
  }
  __syncthreads();
  {
    float m1p = 0.f;
    #pragma unroll 4
    for (int dd = q * 32; dd < q * 32 + 32; ++dd)
      m1p = fmaf(hl[dd], Wm1T[dd * 128 + d], m1p);
    macc[q][d] = m1p;
  }
  __syncthreads();
  if (q == 0) m1s[d] = fmaxf(macc[0][d] + macc[1][d] + macc[2][d] + macc[3][d] + bm1[d], 0.f);
  __syncthreads();
  {
    float m2p = 0.f;
    #pragma unroll 4
    for (int dd = q * 32; dd < q * 32 + 32; ++dd)
      m2p = fmaf(m1s[dd], Wm2T[dd * 128 + d], m2p);
    macc[q][d] = m2p;
  }
  __syncthreads();
  if (q == 0) {
    float u = grus[d] + macc[0][d] + macc[1][d] + macc[2][d] + macc[3][d] + bm2[d];
    float val = (s2v - 2.0f * u * un + u * u * den) / den;
    float ls = 0.5f * logf(fmaxf(val, 0.0f) + EPS_);
    slots[bi * 256 + d]       = u;
    slots[bi * 256 + 128 + d] = ls;
    uarr[d] = u; uarr[128 + d] = ls;
    if (d == 0) pi[bi] = den;
  }
  __syncthreads();
  if (do_s1) {
    __shared__ float2 wr4[4];
    __shared__ float sln[256];
    __shared__ float qacc[2][2][128];
    __shared__ float qs_l[128], ivs_l[128];
    __shared__ float wrC[8];
    if (t < 256) {
      float v2 = uarr[t];
      float s = v2, ssq = v2 * v2;
      #pragma unroll
      for (int o = 32; o > 0; o >>= 1) { s += __shfl_down(s, o); ssq += __shfl_down(ssq, o); }
      if ((t & 63) == 0) wr4[t >> 6] = make_float2(s, ssq);
    }
    __syncthreads();
    if (t < 256) {
      float fs  = wr4[0].x + wr4[1].x + wr4[2].x + wr4[3].x;
      float fss = wr4[0].y + wr4[1].y + wr4[2].y + wr4[3].y;
      float m   = fs * (1.0f/256.0f);
      float var = fss * (1.0f/256.0f) - m * m;
      sln[t] = (uarr[t] - m) * rsqrtf(var + 1e-5f) * gs[t] + bs[t];
    }
    __syncthreads();
    {
      int h2 = t >> 8, qq = (t >> 7) & 1, d2 = t & 127;
      const float* src = sln + h2 * 128;
      float acc = 0.f;
      #pragma unroll 4
      for (int dd = qq * 64; dd < qq * 64 + 64; ++dd)
        acc = fmaf(src[dd], WqT[dd * 128 + d2], acc);
      qacc[h2][qq][d2] = acc;
    }
    __syncthreads();
    if (t < 128) {
      qs_l[t] = qacc[0][0][t] + qacc[0][1][t];
      mus[bi * 128 + t] = sln[t];
    } else if (t < 256) {
      int dd2 = t - 128;
      ivs_l[dd2] = expf(-2.0f * (qacc[1][0][dd2] + qacc[1][1][dd2]));
    }
    __syncthreads();
    float cp = 0.f;
    if (t < 128) {
      float iv = ivs_l[t], qv = qs_l[t];
      wAo[bi * 128 + t] = iv;
      wBo[bi * 128 + t] = -2.0f * qv * iv;
      cp = qv * qv * iv;
    }
    #pragma unroll
    for (int o = 32; o > 0; o >>= 1) cp += __shfl_down(cp, o);
    if ((t & 63) == 0) wrC[t >> 6] = cp;
    __syncthreads();
    if (t == 0) czo[bi] = wrC[0] + wrC[1];
  } else {
    __shared__ float oacc[2][256];
    __shared__ float hh[256];
    {
      int o = t & 255, qq = t >> 8;
      float acc = 0.f;
      #pragma unroll 4
      for (int dd = qq * 128; dd < qq * 128 + 128; ++dd)
        acc = fmaf(uarr[dd], Wo1T[dd * 256 + o], acc);
      oacc[qq][o] = acc;
    }
    __syncthreads();
    if (t < 256) hh[t] = fmaxf(oacc[0][t] + oacc[1][t] + bo1[t], 0.f);
    __syncthreads();
    {
      int o2 = t & 127, q4 = t >> 7;
      float acc2 = 0.f;
      #pragma unroll 4
      for (int dd = q4 * 64; dd < q4 * 64 + 64; ++dd)
        acc2 = fmaf(hh[dd], Wo2T[dd * 128 + o2], acc2);
      macc[q4][o2] = acc2;
    }
    __syncthreads();
    if (t < 128) out[bi * 128 + t] = macc[0][t] + macc[1][t] + macc[2][t] + macc[3][t] + bo2[t];
  }
}

// ---------------------------------------------------------------------------
extern "C" void kernel_launch(void* const* d_in, const int* in_sizes, int n_in,
                              void* d_out, int out_size, void* d_ws, size_t ws_size,
                              hipStream_t stream) {
  const float* inputs = (const float*)d_in[0];
  const float* noise  = (const float*)d_in[1];
  const float* smu    = (const float*)d_in[2];
  const float* sls    = (const float*)d_in[3];
  const float* Wq     = (const float*)d_in[4];
  const float* Wk     = (const float*)d_in[5];
  const float* Wih    = (const float*)d_in[6];
  const float* Whh    = (const float*)d_in[7];
  const float* bih    = (const float*)d_in[8];
  const float* bhh    = (const float*)d_in[9];
  const float* Wm1    = (const float*)d_in[10];
  const float* bm1    = (const float*)d_in[11];
  const float* Wm2    = (const float*)d_in[12];
  const float* bm2    = (const float*)d_in[13];
  const float* gin    = (const float*)d_in[14];
  const float* bin    = (const float*)d_in[15];
  const float* gsl    = (const float*)d_in[16];
  const float* bsl    = (const float*)d_in[17];
  const float* gmu    = (const float*)d_in[18];
  const float* bmu    = (const float*)d_in[19];
  const float* Wo1    = (const float*)d_in[20];
  const float* bo1    = (const float*)d_in[21];
  const float* Wo2    = (const float*)d_in[22];
  const float* bo2    = (const float*)d_in[23];

  float* ws    = (float*)d_ws;
  float* kbuf  = ws + OFF_K;
  float* WqT   = ws + OFF_WQT;
  float* WkT   = ws + OFF_WKT;
  float* WihT  = ws + OFF_WIHT;
  float* WhhT  = ws + OFF_WHHT;
  float* Wm1T  = ws + OFF_WM1T;
  float* Wm2T  = ws + OFF_WM2T;
  float* Wo1T  = ws + OFF_WO1T;
  float* Wo2T  = ws + OFF_WO2T;
  float* slots = ws + OFF_SLOTS;
  float* pibuf = ws + OFF_PI;
  float* mus   = ws + OFF_MUS;
  float* wA    = ws + OFF_WA;
  float* wB    = ws + OFF_WB;
  float* wun   = ws + OFF_UN;
  float* ws2   = ws + OFF_S2;
  float* wden  = ws + OFF_DEN;
  float* czb   = ws + OFF_CZ;

  hipLaunchKernelGGL(init_kernel, dim3(1153), dim3(256), 0, stream,
                     Wq, Wk, Wih, Whh, Wm1, Wm2, Wo1, Wo2, smu, sls, noise, ws);
  hipLaunchKernelGGL(k_kernel, dim3(512), dim3(256), 0, stream,
                     inputs, gin, bin, WkT, kbuf);
  hipLaunchKernelGGL(s1_kernel, dim3(128), dim3(256), 0, stream,
                     slots, gsl, bsl, WqT, mus, wA, wB, czb);
  for (int s = 0; s < 4; ++s) {
    hipLaunchKernelGGL(s2_kernel, dim3(32, 16), dim3(512), 0, stream,
                       kbuf, wA, wB, czb, pibuf, wun, ws2, wden);
    hipLaunchKernelGGL(s3_kernel, dim3(128), dim3(512), 0, stream,
                       wun, ws2, wden, WihT, WhhT, bih, bhh,
                       Wm1T, bm1, Wm2T, bm2, gmu, bmu, slots, pibuf,
                       (s < 3) ? 1 : 0, gsl, bsl, WqT, mus, wA, wB, czb,
                       Wo1T, bo1, Wo2T, bo2, (float*)d_out);
  }
}

// Round 10
// 174.891 us; speedup vs baseline: 4.6947x; 1.0077x over previous
//
#include <hip/hip_runtime.h>

#define EPS_ 1e-8f

// sizes: B=16, N=2048, D=128, NS=8, H=128, steps=4
constexpr int OFF_K     = 0;                       // 16*2048*128 = 4194304
constexpr int OFF_WQT   = 4194304;                 // 16384
constexpr int OFF_WKT   = OFF_WQT  + 16384;
constexpr int OFF_WIHT  = OFF_WKT  + 16384;        // 49152
constexpr int OFF_WHHT  = OFF_WIHT + 49152;        // 49152
constexpr int OFF_WM1T  = OFF_WHHT + 49152;        // 16384
constexpr int OFF_WM2T  = OFF_WM1T + 16384;        // 16384
constexpr int OFF_WO1T  = OFF_WM2T + 16384;        // 65536
constexpr int OFF_WO2T  = OFF_WO1T + 65536;        // 32768
constexpr int OFF_SLOTS = OFF_WO2T + 32768;        // 32768
constexpr int OFF_PI    = OFF_SLOTS+ 32768;        // 128
constexpr int OFF_MUS   = OFF_PI   + 128;          // 16384
constexpr int OFF_WA    = OFF_MUS  + 16384;        // 16384 (iv)
constexpr int OFF_WB    = OFF_WA   + 16384;        // 16384 (-2*q*iv)
constexpr int OFF_UN    = OFF_WB   + 16384;        // 16*32*8*128 = 524288
constexpr int OFF_S2    = OFF_UN   + 524288;       // 524288
constexpr int OFF_DEN   = OFF_S2   + 524288;       // 16*32*8 = 4096
constexpr int OFF_CZ    = OFF_DEN  + 4096;         // 128

// ---------------------------------------------------------------------------
__global__ __launch_bounds__(256) void init_kernel(
    const float* __restrict__ Wq,  const float* __restrict__ Wk,
    const float* __restrict__ Wih, const float* __restrict__ Whh,
    const float* __restrict__ Wm1, const float* __restrict__ Wm2,
    const float* __restrict__ Wo1, const float* __restrict__ Wo2,
    const float* __restrict__ smu, const float* __restrict__ sls,
    const float* __restrict__ noise, float* __restrict__ ws) {
  int idx = blockIdx.x * 256 + threadIdx.x;
  if (idx < 16384) { int j = idx >> 7, d = idx & 127; ws[OFF_WQT + d*128 + j] = Wq[idx]; return; }
  idx -= 16384;
  if (idx < 16384) { int j = idx >> 7, d = idx & 127; ws[OFF_WKT + d*128 + j] = Wk[idx]; return; }
  idx -= 16384;
  if (idx < 49152) { int j = idx >> 7, d = idx & 127; ws[OFF_WIHT + d*384 + j] = Wih[idx]; return; }
  idx -= 49152;
  if (idx < 49152) { int j = idx >> 7, d = idx & 127; ws[OFF_WHHT + d*384 + j] = Whh[idx]; return; }
  idx -= 49152;
  if (idx < 16384) { int j = idx >> 7, d = idx & 127; ws[OFF_WM1T + d*128 + j] = Wm1[idx]; return; }
  idx -= 16384;
  if (idx < 16384) { int j = idx >> 7, d = idx & 127; ws[OFF_WM2T + d*128 + j] = Wm2[idx]; return; }
  idx -= 16384;
  if (idx < 65536) { int j = idx >> 8, d = idx & 255; ws[OFF_WO1T + d*256 + j] = Wo1[idx]; return; }
  idx -= 65536;
  if (idx < 32768) { int j = idx >> 8, m = idx & 255; ws[OFF_WO2T + m*128 + j] = Wo2[idx]; return; }
  idx -= 32768;
  if (idx < 32768) { int c = idx & 255; ws[OFF_SLOTS + idx] = smu[c] + expf(sls[c]) * noise[idx]; return; }
  idx -= 32768;
  if (idx < 128) { ws[OFF_PI + idx] = 0.125f; }
}

// ---------------------------------------------------------------------------
// Merged k + s1 dispatch: blocks [0,512) compute k = LN(inputs)@Wk.T
// (r9's R8xJ4 structure); blocks [512,640) run the initial s1.
__global__ __launch_bounds__(256) void ks1_kernel(
    const float* __restrict__ xin, const float* __restrict__ g, const float* __restrict__ bb,
    const float* __restrict__ WkT, float* __restrict__ kout,
    const float* __restrict__ slots, const float* __restrict__ gsl, const float* __restrict__ bsl,
    const float* __restrict__ WqT, float* __restrict__ mus,
    float* __restrict__ wA, float* __restrict__ wB, float* __restrict__ cz) {
  __shared__ float xsT[128][72];     // 36.9KB, d-major (k); scratch carved for s1
  __shared__ float2 red2[64][4];
  __shared__ float mrow[64], srow[64];
  int t = threadIdx.x;
  if (blockIdx.x < 512) {
    // ---------------- k body ----------------
    long long base = (long long)blockIdx.x * 64 * 128;
    int r = t >> 2, q = t & 3;
    float vals[32];
    {
      const float4* src = (const float4*)(xin + base + r * 128 + q * 32);
      #pragma unroll
      for (int i = 0; i < 8; ++i) *(float4*)&vals[i * 4] = src[i];
    }
    {
      float s = 0.f, ss = 0.f;
      #pragma unroll
      for (int i = 0; i < 32; ++i) { float v = vals[i]; s += v; ss = fmaf(v, v, ss); }
      red2[r][q] = make_float2(s, ss);
    }
    __syncthreads();
    if (t < 64) {
      float s = 0.f, ss = 0.f;
      #pragma unroll
      for (int c = 0; c < 4; ++c) { float2 p = red2[t][c]; s += p.x; ss += p.y; }
      float m = s * (1.0f / 128.0f);
      float var = ss * (1.0f / 128.0f) - m * m;
      mrow[t] = m; srow[t] = rsqrtf(var + 1e-5f);
    }
    __syncthreads();
    {
      float m = mrow[r], is = srow[r];
      #pragma unroll 8
      for (int u = 0; u < 32; ++u) {
        int d = q * 32 + u;
        xsT[d][r] = (vals[u] - m) * is * g[d] + bb[d];
      }
    }
    __syncthreads();
    int j4 = t & 31, rg = t >> 5;
    int r0 = rg * 8;
    float a0[8], a1[8], a2[8], a3[8];
    #pragma unroll
    for (int i = 0; i < 8; ++i) { a0[i] = 0.f; a1[i] = 0.f; a2[i] = 0.f; a3[i] = 0.f; }
    #pragma unroll 2
    for (int d = 0; d < 128; ++d) {
      float4 wv = *(const float4*)(WkT + d * 128 + j4 * 4);
      float4 x0 = *(const float4*)&xsT[d][r0];
      float4 x1 = *(const float4*)&xsT[d][r0 + 4];
      a0[0] = fmaf(x0.x, wv.x, a0[0]); a1[0] = fmaf(x0.x, wv.y, a1[0]);
      a2[0] = fmaf(x0.x, wv.z, a2[0]); a3[0] = fmaf(x0.x, wv.w, a3[0]);
      a0[1] = fmaf(x0.y, wv.x, a0[1]); a1[1] = fmaf(x0.y, wv.y, a1[1]);
      a2[1] = fmaf(x0.y, wv.z, a2[1]); a3[1] = fmaf(x0.y, wv.w, a3[1]);
      a0[2] = fmaf(x0.z, wv.x, a0[2]); a1[2] = fmaf(x0.z, wv.y, a1[2]);
      a2[2] = fmaf(x0.z, wv.z, a2[2]); a3[2] = fmaf(x0.z, wv.w, a3[2]);
      a0[3] = fmaf(x0.w, wv.x, a0[3]); a1[3] = fmaf(x0.w, wv.y, a1[3]);
      a2[3] = fmaf(x0.w, wv.z, a2[3]); a3[3] = fmaf(x0.w, wv.w, a3[3]);
      a0[4] = fmaf(x1.x, wv.x, a0[4]); a1[4] = fmaf(x1.x, wv.y, a1[4]);
      a2[4] = fmaf(x1.x, wv.z, a2[4]); a3[4] = fmaf(x1.x, wv.w, a3[4]);
      a0[5] = fmaf(x1.y, wv.x, a0[5]); a1[5] = fmaf(x1.y, wv.y, a1[5]);
      a2[5] = fmaf(x1.y, wv.z, a2[5]); a3[5] = fmaf(x1.y, wv.w, a3[5]);
      a0[6] = fmaf(x1.z, wv.x, a0[6]); a1[6] = fmaf(x1.z, wv.y, a1[6]);
      a2[6] = fmaf(x1.z, wv.z, a2[6]); a3[6] = fmaf(x1.z, wv.w, a3[6]);
      a0[7] = fmaf(x1.w, wv.x, a0[7]); a1[7] = fmaf(x1.w, wv.y, a1[7]);
      a2[7] = fmaf(x1.w, wv.z, a2[7]); a3[7] = fmaf(x1.w, wv.w, a3[7]);
    }
    #pragma unroll
    for (int i = 0; i < 8; ++i) {
      float* o = kout + base + (long long)(r0 + i) * 128 + j4 * 4;
      *(float4*)o = make_float4(a0[i], a1[i], a2[i], a3[i]);
    }
  } else {
    // ---------------- s1 body (bi = blockIdx.x - 512) ----------------
    int bi = blockIdx.x - 512;
    float* f = &xsT[0][0];
    float* sl    = f;          // [256]
    float* qs_l  = f + 256;    // [128]
    float* ivs_l = f + 384;    // [128]
    float2* wr   = (float2*)(f + 512);  // [4]
    float* wrC   = f + 520;    // [4]
    float v = slots[bi * 256 + t];
    float s = v, ss = v * v;
    #pragma unroll
    for (int o = 32; o > 0; o >>= 1) { s += __shfl_down(s, o); ss += __shfl_down(ss, o); }
    if ((t & 63) == 0) wr[t >> 6] = make_float2(s, ss);
    __syncthreads();
    float fs  = wr[0].x + wr[1].x + wr[2].x + wr[3].x;
    float fss = wr[0].y + wr[1].y + wr[2].y + wr[3].y;
    float m   = fs * (1.0f/256.0f);
    float var = fss * (1.0f/256.0f) - m * m;
    float isr = rsqrtf(var + 1e-5f);
    float sn  = (v - m) * isr * gsl[t] + bsl[t];
    sl[t] = sn;
    __syncthreads();
    if (t < 128) {
      float acc = 0.f;
      #pragma unroll 4
      for (int d = 0; d < 128; ++d) acc = fmaf(sl[d], WqT[d * 128 + t], acc);
      qs_l[t] = acc;
      mus[bi * 128 + t] = sn;
    } else {
      int jj = t - 128;
      float acc = 0.f;
      #pragma unroll 4
      for (int d = 0; d < 128; ++d) acc = fmaf(sl[128 + d], WqT[d * 128 + jj], acc);
      ivs_l[jj] = expf(-2.0f * acc);
    }
    __syncthreads();
    float cp = 0.f;
    if (t < 128) {
      float iv = ivs_l[t], q = qs_l[t];
      wA[bi * 128 + t] = iv;
      wB[bi * 128 + t] = -2.0f * q * iv;
      cp = q * q * iv;
    }
    #pragma unroll
    for (int o = 32; o > 0; o >>= 1) cp += __shfl_down(cp, o);
    if ((t & 63) == 0) wrC[t >> 6] = cp;
    __syncthreads();
    if (t == 0) cz[bi] = wrC[0] + wrC[1];
  }
}

// ---------------------------------------------------------------------------
// S2 v7: 64-n chunk, grid (32,16), 1024 threads -> 2 blocks/CU = 32 waves/CU.
// phase1 (t<512): r8's proven 2-n blocked compute. phase2: 1 slot per thread.
__global__ __launch_bounds__(1024) void s2_kernel(
    const float* __restrict__ kmat, const float* __restrict__ wA,
    const float* __restrict__ wB,  const float* __restrict__ cz,
    const float* __restrict__ pi,
    float* __restrict__ wun, float* __restrict__ ws2, float* __restrict__ wden) {
  __shared__ float pdots[16][64][8];  // 32KB
  __shared__ float es[64][9];
  __shared__ float recip[64];
  __shared__ float gT[8][72];
  __shared__ float pd[8][8];
  __shared__ float pisl[8], czl[8];
  int t = threadIdx.x;
  int chunk = blockIdx.x, b = blockIdx.y;
  if (t < 8) { pisl[t] = pi[b * 8 + t]; czl[t] = cz[b * 8 + t]; }
  // ---- phase 1 (t<512): thread (w = t&15, nt = t>>4 -> n0 = 2nt, n0+1)
  if (t < 512) {
    int w = t & 15, nt = t >> 4;
    int n0 = nt * 2;
    const float4* kr4 = (const float4*)(kmat + (long long)(b * 2048 + chunk * 64) * 128);
    const float4* wa4 = (const float4*)(wA + b * 1024);
    const float4* wb4 = (const float4*)(wB + b * 1024);
    float acc0[8] = {0,0,0,0,0,0,0,0};
    float acc1[8] = {0,0,0,0,0,0,0,0};
    #pragma unroll
    for (int i = 0; i < 2; ++i) {
      int gg = i * 16 + w;
      float4 k0 = kr4[n0 * 32 + gg];
      float4 k1 = kr4[(n0 + 1) * 32 + gg];
      float x0 = k0.x * k0.x, y0 = k0.y * k0.y, z0 = k0.z * k0.z, w0 = k0.w * k0.w;
      float x1 = k1.x * k1.x, y1 = k1.y * k1.y, z1 = k1.z * k1.z, w1 = k1.w * k1.w;
      #pragma unroll
      for (int s = 0; s < 8; ++s) {
        float4 a4 = wa4[s * 32 + gg];
        float4 b4 = wb4[s * 32 + gg];
        float c0 = acc0[s], c1 = acc1[s];
        c0 = fmaf(x0, a4.x, c0); c0 = fmaf(k0.x, b4.x, c0);
        c0 = fmaf(y0, a4.y, c0); c0 = fmaf(k0.y, b4.y, c0);
        c0 = fmaf(z0, a4.z, c0); c0 = fmaf(k0.z, b4.z, c0);
        c0 = fmaf(w0, a4.w, c0); c0 = fmaf(k0.w, b4.w, c0);
        c1 = fmaf(x1, a4.x, c1); c1 = fmaf(k1.x, b4.x, c1);
        c1 = fmaf(y1, a4.y, c1); c1 = fmaf(k1.y, b4.y, c1);
        c1 = fmaf(z1, a4.z, c1); c1 = fmaf(k1.z, b4.z, c1);
        c1 = fmaf(w1, a4.w, c1); c1 = fmaf(k1.w, b4.w, c1);
        acc0[s] = c0; acc1[s] = c1;
      }
    }
    *(float4*)&pdots[w][n0][0]     = make_float4(acc0[0], acc0[1], acc0[2], acc0[3]);
    *(float4*)&pdots[w][n0][4]     = make_float4(acc0[4], acc0[5], acc0[6], acc0[7]);
    *(float4*)&pdots[w][n0 + 1][0] = make_float4(acc1[0], acc1[1], acc1[2], acc1[3]);
    *(float4*)&pdots[w][n0 + 1][4] = make_float4(acc1[4], acc1[5], acc1[6], acc1[7]);
  }
  __syncthreads();
  // ---- reduce over 16 w-groups + exp (t<512): thread (n2 = t>>3, s = t&7)
  float e = 0.f;
  if (t < 512) {
    int n2 = t >> 3, s = t & 7;
    float dots = czl[s];
    #pragma unroll
    for (int w = 0; w < 16; ++w) dots += pdots[w][n2][s];
    e = (expf(-dots) + EPS_) * pisl[s];
    es[n2][s] = e;
  }
  __syncthreads();
  if (t < 64) {
    float ssum = 0.f;
    #pragma unroll
    for (int s = 0; s < 8; ++s) ssum += es[t][s];
    recip[t] = 1.0f / ssum;
  }
  __syncthreads();
  // ---- gammas + den partials (t<512)
  if (t < 512) {
    int n2 = t >> 3, s = t & 7;
    float gam = e * recip[n2];
    gT[s][n2] = gam;
    float p = gam;
    p += __shfl_down(p, 8); p += __shfl_down(p, 16); p += __shfl_down(p, 32);
    if ((t & 63) < 8) pd[t >> 6][t & 7] = p;
  }
  __syncthreads();
  if (t < 8) {
    float sden = 0.f;
    #pragma unroll
    for (int w = 0; w < 8; ++w) sden += pd[w][t];
    wden[(b * 32 + chunk) * 8 + t] = sden;
  }
  // ---- phase 2 (all 1024): thread (d = t&127, s = t>>7 in [0,8))
  {
    int d = t & 127, sh = t >> 7;
    const float* kcol = kmat + (long long)(b * 2048 + chunk * 64) * 128 + d;
    float u0 = 0.f, q0 = 0.f, u1 = 0.f, q1 = 0.f;
    #pragma unroll 2
    for (int n3 = 0; n3 < 64; n3 += 4) {
      float4 ga = *(const float4*)&gT[sh][n3];
      float k0 = kcol[(n3 + 0) * 128];
      float k1 = kcol[(n3 + 1) * 128];
      float k2 = kcol[(n3 + 2) * 128];
      float k3 = kcol[(n3 + 3) * 128];
      u0 = fmaf(ga.x, k0, u0); q0 = fmaf(ga.x, k0 * k0, q0);
      u1 = fmaf(ga.y, k1, u1); q1 = fmaf(ga.y, k1 * k1, q1);
      u0 = fmaf(ga.z, k2, u0); q0 = fmaf(ga.z, k2 * k2, q0);
      u1 = fmaf(ga.w, k3, u1); q1 = fmaf(ga.w, k3 * k3, q1);
    }
    // NOTE: combine pairs at the end; ordering (even-n chain + odd-n chain)
    int pb = ((b * 32 + chunk) * 8 + sh) * 128 + d;
    wun[pb] = u0 + u1;
    ws2[pb] = q0 + q1;
  }
}

// ---------------------------------------------------------------------------
// S3 fused: reduce(32 chunks) + GRU + LN + MLP + upd_ls + slots/pi; then
// next-iter S1 (emitting wA/wB/cz) or the final output MLP.  (unchanged)
__global__ __launch_bounds__(512) void s3_kernel(
    const float* __restrict__ wun, const float* __restrict__ ws2, const float* __restrict__ wden,
    const float* __restrict__ WihT, const float* __restrict__ WhhT,
    const float* __restrict__ bih,  const float* __restrict__ bhh,
    const float* __restrict__ Wm1T, const float* __restrict__ bm1,
    const float* __restrict__ Wm2T, const float* __restrict__ bm2,
    const float* __restrict__ gmu,  const float* __restrict__ bmu,
    float* __restrict__ slots, float* __restrict__ pi,
    int do_s1,
    const float* __restrict__ gs, const float* __restrict__ bs,
    const float* __restrict__ WqT,
    float* __restrict__ mus, float* __restrict__ wAo, float* __restrict__ wBo,
    float* __restrict__ czo,
    const float* __restrict__ Wo1T, const float* __restrict__ bo1,
    const float* __restrict__ Wo2T, const float* __restrict__ bo2,
    float* __restrict__ out) {
  int t = threadIdx.x, bi = blockIdx.x;
  int d = t & 127, q = t >> 7;      // q in [0,4)
  int b = bi >> 3, i = bi & 7;
  __shared__ float redU[4][128], redS[4][128];
  __shared__ float dred[32];
  __shared__ float xs[128], hs[128];
  __shared__ float gacc[4][6][128];
  __shared__ float ga[6][128];
  __shared__ float grus[128], hl[128], m1s[128];
  __shared__ float macc[4][128];
  __shared__ float2 wr2[2];
  __shared__ float uarr[256];
  float unp = 0.f, s2p = 0.f;
  #pragma unroll
  for (int c = q * 8; c < q * 8 + 8; ++c) {
    int po = ((b * 32 + c) * 8 + i) * 128 + d;
    unp += wun[po]; s2p += ws2[po];
  }
  redU[q][d] = unp; redS[q][d] = s2p;
  if (t < 32) dred[t] = wden[(b * 32 + t) * 8 + i];
  if (q == 1) hs[d] = mus[bi * 128 + d];
  __syncthreads();
  float den = 0.f;
  #pragma unroll
  for (int c = 0; c < 32; ++c) den += dred[c];
  float un  = redU[0][d] + redU[1][d] + redU[2][d] + redU[3][d];
  float s2v = redS[0][d] + redS[1][d] + redS[2][d] + redS[3][d];
  if (q == 0) xs[d] = un / den;
  __syncthreads();
  {
    float a0 = 0, a1 = 0, a2 = 0, a3 = 0, a4 = 0, a5 = 0;
    #pragma unroll 4
    for (int dd = q * 32; dd < q * 32 + 32; ++dd) {
      float xv = xs[dd], hv = hs[dd];
      const float* wi = &WihT[dd * 384 + d];
      const float* wh = &WhhT[dd * 384 + d];
      a0 = fmaf(xv, wi[0],   a0);
      a1 = fmaf(xv, wi[128], a1);
      a2 = fmaf(xv, wi[256], a2);
      a3 = fmaf(hv, wh[0],   a3);
      a4 = fmaf(hv, wh[128], a4);
      a5 = fmaf(hv, wh[256], a5);
    }
    gacc[q][0][d] = a0; gacc[q][1][d] = a1; gacc[q][2][d] = a2;
    gacc[q][3][d] = a3; gacc[q][4][d] = a4; gacc[q][5][d] = a5;
  }
  __syncthreads();
  for (int f = t; f < 768; f += 512) {
    int j = f >> 7, dd = f & 127;
    ga[j][dd] = gacc[0][j][dd] + gacc[1][j][dd] + gacc[2][j][dd] + gacc[3][j][dd];
  }
  __syncthreads();
  float gru = 0.f;
  if (q == 0) {
    float ir = ga[0][d] + bih[d], iz = ga[1][d] + bih[128 + d], inn = ga[2][d] + bih[256 + d];
    float hr = ga[3][d] + bhh[d], hz = ga[4][d] + bhh[128 + d], hn  = ga[5][d] + bhh[256 + d];
    float r  = 1.0f / (1.0f + expf(-(ir + hr)));
    float z  = 1.0f / (1.0f + expf(-(iz + hz)));
    float nn = tanhf(inn + r * hn);
    gru = (1.0f - z) * nn + z * hs[d];
    grus[d] = gru;
    float s = gru, ssq = gru * gru;
    #pragma unroll
    for (int o = 32; o > 0; o >>= 1) { s += __shfl_down(s, o); ssq += __shfl_down(ssq, o); }
    if ((d & 63) == 0) wr2[d >> 6] = make_float2(s, ssq);
  }
  __syncthreads();
  if (q == 0) {
    float fs = wr2[0].x + wr2[1].x, fss = wr2[0].y + wr2[1].y;
    float mean = fs * (1.0f/128.0f);
    float var  = fss * (1.0f/128.0f) - mean * mean;
    hl[d] = (gru - mean) * rsqrtf(var + 1e-5f) * gmu[d] + bmu[d];
  }
  __syncthreads();
  {
    float m1p = 0.f;
    #pragma unroll 4
    for (int dd = q * 32; dd < q * 32 + 32; ++dd)
      m1p = fmaf(hl[dd], Wm1T[dd * 128 + d], m1p);
    macc[q][d] = m1p;
  }
  __syncthreads();
  if (q == 0) m1s[d] = fmaxf(macc[0][d] + macc[1][d] + macc[2][d] + macc[3][d] + bm1[d], 0.f);
  __syncthreads();
  {
    float m2p = 0.f;
    #pragma unroll 4
    for (int dd = q * 32; dd < q * 32 + 32; ++dd)
      m2p = fmaf(m1s[dd], Wm2T[dd * 128 + d], m2p);
    macc[q][d] = m2p;
  }
  __syncthreads();
  if (q == 0) {
    float u = grus[d] + macc[0][d] + macc[1][d] + macc[2][d] + macc[3][d] + bm2[d];
    float val = (s2v - 2.0f * u * un + u * u * den) / den;
    float ls = 0.5f * logf(fmaxf(val, 0.0f) + EPS_);
    slots[bi * 256 + d]       = u;
    slots[bi * 256 + 128 + d] = ls;
    uarr[d] = u; uarr[128 + d] = ls;
    if (d == 0) pi[bi] = den;
  }
  __syncthreads();
  if (do_s1) {
    __shared__ float2 wr4[4];
    __shared__ float sln[256];
    __shared__ float qacc[2][2][128];
    __shared__ float qs_l[128], ivs_l[128];
    __shared__ float wrC[8];
    if (t < 256) {
      float v2 = uarr[t];
      float s = v2, ssq = v2 * v2;
      #pragma unroll
      for (int o = 32; o > 0; o >>= 1) { s += __shfl_down(s, o); ssq += __shfl_down(ssq, o); }
      if ((t & 63) == 0) wr4[t >> 6] = make_float2(s, ssq);
    }
    __syncthreads();
    if (t < 256) {
      float fs  = wr4[0].x + wr4[1].x + wr4[2].x + wr4[3].x;
      float fss = wr4[0].y + wr4[1].y + wr4[2].y + wr4[3].y;
      float m   = fs * (1.0f/256.0f);
      float var = fss * (1.0f/256.0f) - m * m;
      sln[t] = (uarr[t] - m) * rsqrtf(var + 1e-5f) * gs[t] + bs[t];
    }
    __syncthreads();
    {
      int h2 = t >> 8, qq = (t >> 7) & 1, d2 = t & 127;
      const float* src = sln + h2 * 128;
      float acc = 0.f;
      #pragma unroll 4
      for (int dd = qq * 64; dd < qq * 64 + 64; ++dd)
        acc = fmaf(src[dd], WqT[dd * 128 + d2], acc);
      qacc[h2][qq][d2] = acc;
    }
    __syncthreads();
    if (t < 128) {
      qs_l[t] = qacc[0][0][t] + qacc[0][1][t];
      mus[bi * 128 + t] = sln[t];
    } else if (t < 256) {
      int dd2 = t - 128;
      ivs_l[dd2] = expf(-2.0f * (qacc[1][0][dd2] + qacc[1][1][dd2]));
    }
    __syncthreads();
    float cp = 0.f;
    if (t < 128) {
      float iv = ivs_l[t], qv = qs_l[t];
      wAo[bi * 128 + t] = iv;
      wBo[bi * 128 + t] = -2.0f * qv * iv;
      cp = qv * qv * iv;
    }
    #pragma unroll
    for (int o = 32; o > 0; o >>= 1) cp += __shfl_down(cp, o);
    if ((t & 63) == 0) wrC[t >> 6] = cp;
    __syncthreads();
    if (t == 0) czo[bi] = wrC[0] + wrC[1];
  } else {
    __shared__ float oacc[2][256];
    __shared__ float hh[256];
    {
      int o = t & 255, qq = t >> 8;
      float acc = 0.f;
      #pragma unroll 4
      for (int dd = qq * 128; dd < qq * 128 + 128; ++dd)
        acc = fmaf(uarr[dd], Wo1T[dd * 256 + o], acc);
      oacc[qq][o] = acc;
    }
    __syncthreads();
    if (t < 256) hh[t] = fmaxf(oacc[0][t] + oacc[1][t] + bo1[t], 0.f);
    __syncthreads();
    {
      int o2 = t & 127, q4 = t >> 7;
      float acc2 = 0.f;
      #pragma unroll 4
      for (int dd = q4 * 64; dd < q4 * 64 + 64; ++dd)
        acc2 = fmaf(hh[dd], Wo2T[dd * 128 + o2], acc2);
      macc[q4][o2] = acc2;
    }
    __syncthreads();
    if (t < 128) out[bi * 128 + t] = macc[0][t] + macc[1][t] + macc[2][t] + macc[3][t] + bo2[t];
  }
}

// ---------------------------------------------------------------------------
extern "C" void kernel_launch(void* const* d_in, const int* in_sizes, int n_in,
                              void* d_out, int out_size, void* d_ws, size_t ws_size,
                              hipStream_t stream) {
  const float* inputs = (const float*)d_in[0];
  const float* noise  = (const float*)d_in[1];
  const float* smu    = (const float*)d_in[2];
  const float* sls    = (const float*)d_in[3];
  const float* Wq     = (const float*)d_in[4];
  const float* Wk     = (const float*)d_in[5];
  const float* Wih    = (const float*)d_in[6];
  const float* Whh    = (const float*)d_in[7];
  const float* bih    = (const float*)d_in[8];
  const float* bhh    = (const float*)d_in[9];
  const float* Wm1    = (const float*)d_in[10];
  const float* bm1    = (const float*)d_in[11];
  const float* Wm2    = (const float*)d_in[12];
  const float* bm2    = (const float*)d_in[13];
  const float* gin    = (const float*)d_in[14];
  const float* bin    = (const float*)d_in[15];
  const float* gsl    = (const float*)d_in[16];
  const float* bsl    = (const float*)d_in[17];
  const float* gmu    = (const float*)d_in[18];
  const float* bmu    = (const float*)d_in[19];
  const float* Wo1    = (const float*)d_in[20];
  const float* bo1    = (const float*)d_in[21];
  const float* Wo2    = (const float*)d_in[22];
  const float* bo2    = (const float*)d_in[23];

  float* ws    = (float*)d_ws;
  float* kbuf  = ws + OFF_K;
  float* WqT   = ws + OFF_WQT;
  float* WkT   = ws + OFF_WKT;
  float* WihT  = ws + OFF_WIHT;
  float* WhhT  = ws + OFF_WHHT;
  float* Wm1T  = ws + OFF_WM1T;
  float* Wm2T  = ws + OFF_WM2T;
  float* Wo1T  = ws + OFF_WO1T;
  float* Wo2T  = ws + OFF_WO2T;
  float* slots = ws + OFF_SLOTS;
  float* pibuf = ws + OFF_PI;
  float* mus   = ws + OFF_MUS;
  float* wA    = ws + OFF_WA;
  float* wB    = ws + OFF_WB;
  float* wun   = ws + OFF_UN;
  float* ws2   = ws + OFF_S2;
  float* wden  = ws + OFF_DEN;
  float* czb   = ws + OFF_CZ;

  hipLaunchKernelGGL(init_kernel, dim3(1153), dim3(256), 0, stream,
                     Wq, Wk, Wih, Whh, Wm1, Wm2, Wo1, Wo2, smu, sls, noise, ws);
  hipLaunchKernelGGL(ks1_kernel, dim3(640), dim3(256), 0, stream,
                     inputs, gin, bin, WkT, kbuf,
                     slots, gsl, bsl, WqT, mus, wA, wB, czb);
  for (int s = 0; s < 4; ++s) {
    hipLaunchKernelGGL(s2_kernel, dim3(32, 16), dim3(1024), 0, stream,
                       kbuf, wA, wB, czb, pibuf, wun, ws2, wden);
    hipLaunchKernelGGL(s3_kernel, dim3(128), dim3(512), 0, stream,
                       wun, ws2, wden, WihT, WhhT, bih, bhh,
                       Wm1T, bm1, Wm2T, bm2, gmu, bmu, slots, pibuf,
                       (s < 3) ? 1 : 0, gsl, bsl, WqT, mus, wA, wB, czb,
                       Wo1T, bo1, Wo2T, bo2, (float*)d_out);
  }
}